// Round 10
// baseline (194.528 us; speedup 1.0000x reference)
//
#include <hip/hip_runtime.h>
#include <hip/hip_fp16.h>

#define NB 2
#define RAYS 4096
#define SAMP 96
#define CF 32
#define HID 64
#define HW 256
#define PW 258                  // padded plane width (1-texel zero border)
#define PTEX (PW * PW)          // 66564 texels per plane

constexpr int M_TOTAL = NB * RAYS * SAMP;   // 786432 samples

typedef _Float16 f16x8 __attribute__((ext_vector_type(8)));
typedef float f32x4 __attribute__((ext_vector_type(4)));
typedef int i32x4 __attribute__((ext_vector_type(4)));

__device__ __forceinline__ float softplus_f(float z) {
    return fmaxf(z, 0.f) + __logf(1.f + __expf(-fabsf(z)));
}
__device__ __forceinline__ float sigmoid_f(float z) {
    return __fdividef(1.f, 1.f + __expf(-z));
}

// planes (N,3,C,256,256) f32 -> pt (N*3, 258, 258, C) f16, zero border.
__global__ __launch_bounds__(256)
void k_transposeB(const float* __restrict__ src, __half2* __restrict__ dst) {
    const int xy = blockIdx.x * 256 + threadIdx.x;
    const int pn = blockIdx.y;                    // n*3+p in [0,6)
    if (xy >= PTEX) return;
    const int y = xy / PW;
    const int x = xy - y * PW;
    __half2 v[16];
    if (x >= 1 && x <= HW && y >= 1 && y <= HW) {
        const float* s = src + (((size_t)pn * CF) << 16) + (y - 1) * HW + (x - 1);
        #pragma unroll
        for (int c2 = 0; c2 < 16; ++c2) {
            const float a = s[((size_t)(2 * c2)) << 16];
            const float b = s[((size_t)(2 * c2 + 1)) << 16];
            v[c2] = __floats2half2_rn(a, b);
        }
    } else {
        #pragma unroll
        for (int c2 = 0; c2 < 16; ++c2) v[c2] = __float2half2_rn(0.f);
    }
    __half2* d = dst + ((size_t)pn * PTEX + xy) * 16;
    #pragma unroll
    for (int q = 0; q < 4; ++q)
        ((i32x4*)d)[q] = ((const i32x4*)v)[q];
}

// ---- shared device pieces ----
struct Wreg {
    f16x8 b1f[4];  float b1v[4];
    f16x8 b2f[3][2]; float b2v[3];
};

__device__ __forceinline__ void load_weights(Wreg& w,
        const float* __restrict__ w1, const float* __restrict__ b1,
        const float* __restrict__ w2, const float* __restrict__ b2,
        int g, int ln) {
    #pragma unroll
    for (int Nt = 0; Nt < 4; ++Nt) {
        const int hn = 16 * Nt + ln;
        const float4* p0 = (const float4*)(w1 + hn * CF + g * 8);
        float4 u = p0[0], v = p0[1];
        w.b1f[Nt][0] = (_Float16)u.x; w.b1f[Nt][1] = (_Float16)u.y;
        w.b1f[Nt][2] = (_Float16)u.z; w.b1f[Nt][3] = (_Float16)u.w;
        w.b1f[Nt][4] = (_Float16)v.x; w.b1f[Nt][5] = (_Float16)v.y;
        w.b1f[Nt][6] = (_Float16)v.z; w.b1f[Nt][7] = (_Float16)v.w;
        w.b1v[Nt] = b1[hn];
    }
    #pragma unroll
    for (int Nt2 = 0; Nt2 < 3; ++Nt2) {
        const int o = 16 * Nt2 + ln;
        if (o < 33) {
            #pragma unroll
            for (int kh = 0; kh < 2; ++kh) {
                const float4* p0 = (const float4*)(w2 + o * HID + kh * 32 + g * 8);
                float4 u = p0[0], v = p0[1];
                w.b2f[Nt2][kh][0] = (_Float16)u.x; w.b2f[Nt2][kh][1] = (_Float16)u.y;
                w.b2f[Nt2][kh][2] = (_Float16)u.z; w.b2f[Nt2][kh][3] = (_Float16)u.w;
                w.b2f[Nt2][kh][4] = (_Float16)v.x; w.b2f[Nt2][kh][5] = (_Float16)v.y;
                w.b2f[Nt2][kh][6] = (_Float16)v.z; w.b2f[Nt2][kh][7] = (_Float16)v.w;
            }
            w.b2v[Nt2] = b2[o];
        } else {
            #pragma unroll
            for (int kh = 0; kh < 2; ++kh)
                #pragma unroll
                for (int i = 0; i < 8; ++i) w.b2f[Nt2][kh][i] = (_Float16)0.f;
            w.b2v[Nt2] = 0.f;
        }
    }
}

// 4-lane cooperative gather vs the padded table: no masks/clamps (r9),
// 64B line shared by lanes g=0..3 (r7: 4x fewer TA line-probes).
__device__ __forceinline__ f16x8 gather4(const __half* __restrict__ ptb,
                                         const float* __restrict__ cp, int g) {
    const float c0 = cp[0], c1 = cp[1], c2v = cp[2];
    __half2 acc4[4];
    #pragma unroll
    for (int j = 0; j < 4; ++j) acc4[j] = __float2half2_rn(0.f);

    #pragma unroll
    for (int p = 0; p < 3; ++p) {
        const float u = (p == 2) ? c2v : c0;
        const float v = (p == 0) ? c1 : ((p == 1) ? c2v : c0);
        const float xf = fmaf(u, 128.f, 127.5f);
        const float yf = fmaf(v, 128.f, 127.5f);
        const float x0f = floorf(xf), y0f = floorf(yf);
        const float wx = xf - x0f, wy = yf - y0f;
        const int x0 = (int)x0f, y0 = (int)y0f;        // in [-1, 255]
        const int base = (y0 + 1) * PW + (x0 + 1);      // border handles OOB
        const __half* tp = ptb + (size_t)p * (PTEX * CF) + (size_t)base * CF + g * 8;
        const float w00 = (1.f - wx) * (1.f - wy);
        const float w10 = wx * (1.f - wy);
        const float w01 = (1.f - wx) * wy;
        const float w11 = wx * wy;
        auto tapf = [&](const __half* q, float w) {
            union { float4 f; __half2 h[4]; } u4;
            u4.f = *(const float4*)q;
            const __half2 wh = __float2half2_rn(w);
            acc4[0] = __hfma2(wh, u4.h[0], acc4[0]);
            acc4[1] = __hfma2(wh, u4.h[1], acc4[1]);
            acc4[2] = __hfma2(wh, u4.h[2], acc4[2]);
            acc4[3] = __hfma2(wh, u4.h[3], acc4[3]);
        };
        tapf(tp, w00);
        tapf(tp + CF, w10);
        tapf(tp + PW * CF, w01);
        tapf(tp + PW * CF + CF, w11);
    }
    union { __half2 h[4]; f16x8 f; } uf;
    #pragma unroll
    for (int j = 0; j < 4; ++j) uf.h[j] = acc4[j];
    return uf.f;     // raw sum; 1/3 folded into layer-1 scale
}

constexpr float IS32_3 = 0.058925565098879624f;   // (1/sqrt(32)) / 3

// ============== main path: wave-owns-ray, zero barriers ==============
// Each wave = 1 ray = 96 samples = 6 M-tiles. Composite in-wave via the
// associative (out, T) split: lanes 0-31 fold midpoints 0-46, lanes 32-63
// fold 47-94, combined with one shuffle. No __syncthreads anywhere (r8's
// barrier coupling was the regression); no rgb/sig workspace round-trip.
constexpr int SLICE_C = 13824;  // 96 h-rows * 144
constexpr int SIGO_C = 7680;    // float[96]
constexpr int DEPO_C = 8064;    // float[96]
// rgb: row*80 + c*2 (c=0..31), rows 0..95; h rows row*144 overlap rgb/sig/dep
// but are dead once a2 frags are in registers (in-order DS pipe per wave).

__global__ __launch_bounds__(128)
void k_rayC(const __half2* __restrict__ pt, const float* __restrict__ coords,
            const float* __restrict__ depths,
            const float* __restrict__ w1, const float* __restrict__ b1,
            const float* __restrict__ w2, const float* __restrict__ b2,
            float* __restrict__ out)
{
    __shared__ __align__(16) char sm[2 * SLICE_C];
    const int t = threadIdx.x;
    const int wv = t >> 6;
    const int l = t & 63;
    const int g = l >> 4;
    const int ln = l & 15;
    char* const slice = sm + wv * SLICE_C;

    Wreg w;
    load_weights(w, w1, b1, w2, b2, g, ln);

    const int ray = blockIdx.x * 2 + wv;
    const int base = ray * SAMP;
    const int nb = (ray >= RAYS) ? 1 : 0;
    const __half* ptb = (const __half*)pt + (size_t)nb * 3 * (PTEX * CF);

    // ---- gather 96 samples: 6 A-fragments ----
    f16x8 a1[6];
    #pragma unroll
    for (int Mt = 0; Mt < 6; ++Mt)
        a1[Mt] = gather4(ptb, coords + (size_t)(base + 16 * Mt + ln) * 3, g);

    // ---- layer 1 via MFMA -> h in LDS ----
    #pragma unroll
    for (int Nt = 0; Nt < 4; ++Nt) {
        f32x4 d0 = {0.f, 0.f, 0.f, 0.f};
        f32x4 d1 = {0.f, 0.f, 0.f, 0.f};
        f32x4 d2 = {0.f, 0.f, 0.f, 0.f};
        f32x4 d3 = {0.f, 0.f, 0.f, 0.f};
        f32x4 d4 = {0.f, 0.f, 0.f, 0.f};
        f32x4 d5 = {0.f, 0.f, 0.f, 0.f};
        d0 = __builtin_amdgcn_mfma_f32_16x16x32_f16(a1[0], w.b1f[Nt], d0, 0, 0, 0);
        d1 = __builtin_amdgcn_mfma_f32_16x16x32_f16(a1[1], w.b1f[Nt], d1, 0, 0, 0);
        d2 = __builtin_amdgcn_mfma_f32_16x16x32_f16(a1[2], w.b1f[Nt], d2, 0, 0, 0);
        d3 = __builtin_amdgcn_mfma_f32_16x16x32_f16(a1[3], w.b1f[Nt], d3, 0, 0, 0);
        d4 = __builtin_amdgcn_mfma_f32_16x16x32_f16(a1[4], w.b1f[Nt], d4, 0, 0, 0);
        d5 = __builtin_amdgcn_mfma_f32_16x16x32_f16(a1[5], w.b1f[Nt], d5, 0, 0, 0);
        const int hcol = 16 * Nt + ln;
        #pragma unroll
        for (int Mt = 0; Mt < 6; ++Mt) {
            f32x4 dd = (Mt == 0) ? d0 : (Mt == 1) ? d1 : (Mt == 2) ? d2 :
                       (Mt == 3) ? d3 : (Mt == 4) ? d4 : d5;
            #pragma unroll
            for (int r = 0; r < 4; ++r) {
                const float hv = softplus_f(fmaf(dd[r], IS32_3, w.b1v[Nt]));
                const int row = 16 * Mt + 4 * g + r;
                *(__half*)(slice + row * 144 + hcol * 2) = __float2half(hv);
            }
        }
    }

    // ---- layer-2 A-fragments; then h region is dead ----
    f16x8 a2[6][2];
    #pragma unroll
    for (int Mt = 0; Mt < 6; ++Mt)
        #pragma unroll
        for (int kh = 0; kh < 2; ++kh)
            a2[Mt][kh] = *(const f16x8*)(slice + (16 * Mt + ln) * 144 + (kh * 4 + g) * 16);

    // stage depths (h dead; overlaps h region so must come after a2 loads)
    *(float*)(slice + DEPO_C + l * 4) = depths[base + l];
    if (l < 32)
        *(float*)(slice + DEPO_C + (64 + l) * 4) = depths[base + 64 + l];

    // ---- layer 2 via MFMA -> rgb/sig in LDS ----
    #pragma unroll
    for (int Nt2 = 0; Nt2 < 3; ++Nt2) {
        f32x4 e0 = {0.f, 0.f, 0.f, 0.f};
        f32x4 e1 = {0.f, 0.f, 0.f, 0.f};
        f32x4 e2 = {0.f, 0.f, 0.f, 0.f};
        f32x4 e3 = {0.f, 0.f, 0.f, 0.f};
        f32x4 e4 = {0.f, 0.f, 0.f, 0.f};
        f32x4 e5 = {0.f, 0.f, 0.f, 0.f};
        #pragma unroll
        for (int kh = 0; kh < 2; ++kh) {
            e0 = __builtin_amdgcn_mfma_f32_16x16x32_f16(a2[0][kh], w.b2f[Nt2][kh], e0, 0, 0, 0);
            e1 = __builtin_amdgcn_mfma_f32_16x16x32_f16(a2[1][kh], w.b2f[Nt2][kh], e1, 0, 0, 0);
            e2 = __builtin_amdgcn_mfma_f32_16x16x32_f16(a2[2][kh], w.b2f[Nt2][kh], e2, 0, 0, 0);
            e3 = __builtin_amdgcn_mfma_f32_16x16x32_f16(a2[3][kh], w.b2f[Nt2][kh], e3, 0, 0, 0);
            e4 = __builtin_amdgcn_mfma_f32_16x16x32_f16(a2[4][kh], w.b2f[Nt2][kh], e4, 0, 0, 0);
            e5 = __builtin_amdgcn_mfma_f32_16x16x32_f16(a2[5][kh], w.b2f[Nt2][kh], e5, 0, 0, 0);
        }
        const int o = 16 * Nt2 + ln;
        if (o == 0) {
            #pragma unroll
            for (int Mt = 0; Mt < 6; ++Mt) {
                f32x4 ee = (Mt == 0) ? e0 : (Mt == 1) ? e1 : (Mt == 2) ? e2 :
                           (Mt == 3) ? e3 : (Mt == 4) ? e4 : e5;
                #pragma unroll
                for (int r = 0; r < 4; ++r) {
                    const int row = 16 * Mt + 4 * g + r;
                    *(float*)(slice + SIGO_C + row * 4) = fmaf(ee[r], 0.125f, w.b2v[0]);
                }
            }
        } else if (o < 33) {
            #pragma unroll
            for (int Mt = 0; Mt < 6; ++Mt) {
                f32x4 ee = (Mt == 0) ? e0 : (Mt == 1) ? e1 : (Mt == 2) ? e2 :
                           (Mt == 3) ? e3 : (Mt == 4) ? e4 : e5;
                #pragma unroll
                for (int r = 0; r < 4; ++r) {
                    const float vv = fmaf(ee[r], 0.125f, w.b2v[Nt2]);
                    const float rr = sigmoid_f(vv) * 1.002f - 0.001f;
                    const int row = 16 * Mt + 4 * g + r;
                    *(__half*)(slice + row * 80 + (o - 1) * 2) = __float2half(rr);
                }
            }
        }
    }

    // ---- in-wave split composite (no barrier: same-wave DS is in-order) ----
    const int c = l & 31;
    const int half = l >> 5;
    const int s0 = half * 47;            // segA: mids 0-46; segB: mids 47-94

    auto sigC = [&](int s) -> float {
        return *(const float*)(slice + SIGO_C + s * 4);
    };
    auto depC = [&](int s) -> float {
        return *(const float*)(slice + DEPO_C + s * 4);
    };
    auto rgbC = [&](int s) -> float {
        return __half2float(*(const __half*)(slice + s * 80 + c * 2));
    };

    float T = 1.f, aout = 0.f;
    float sp = sigC(s0), dp = depC(s0), rp = rgbC(s0);
    #pragma unroll 2
    for (int k = 1; k <= 48; ++k) {
        const int s = s0 + k;
        const float sc = sigC(s);
        const float dc = depC(s);
        const float rc = rgbC(s);
        const float dens = softplus_f(0.5f * (sp + sc) - 1.f);
        const float alpha = 1.f - __expf(-(dc - dp) * dens);
        const bool valid = (half == 1) | (k < 48);     // segA does 47 mids
        aout = fmaf(valid ? alpha * T : 0.f, 0.5f * (rp + rc), aout);
        T *= valid ? (1.f - alpha + 1e-10f) : 1.f;
        sp = sc; dp = dc; rp = rc;
    }
    const float outB = __shfl(aout, 32 + c);   // segB partial for channel c
    if (l < 32)
        out[(size_t)ray * CF + c] = fmaf(fmaf(T, outB, aout), 2.f, -1.f);
}

// ============== fallback: direct from planes (no workspace) ==============
constexpr int THREADS = 384;
constexpr int SLICE = 9216;
constexpr int SIG_OFF = 5120;
constexpr int DEP_OFF = 5376;

__device__ __forceinline__ void mlp_slice(char* slice, const f16x8 a1[4],
                                          const Wreg& w, int g, int ln) {
    #pragma unroll
    for (int Nt = 0; Nt < 4; ++Nt) {
        f32x4 d0 = {0.f, 0.f, 0.f, 0.f};
        f32x4 d1 = {0.f, 0.f, 0.f, 0.f};
        f32x4 d2 = {0.f, 0.f, 0.f, 0.f};
        f32x4 d3 = {0.f, 0.f, 0.f, 0.f};
        d0 = __builtin_amdgcn_mfma_f32_16x16x32_f16(a1[0], w.b1f[Nt], d0, 0, 0, 0);
        d1 = __builtin_amdgcn_mfma_f32_16x16x32_f16(a1[1], w.b1f[Nt], d1, 0, 0, 0);
        d2 = __builtin_amdgcn_mfma_f32_16x16x32_f16(a1[2], w.b1f[Nt], d2, 0, 0, 0);
        d3 = __builtin_amdgcn_mfma_f32_16x16x32_f16(a1[3], w.b1f[Nt], d3, 0, 0, 0);
        const int hcol = 16 * Nt + ln;
        #pragma unroll
        for (int Mt = 0; Mt < 4; ++Mt) {
            f32x4 dd = (Mt == 0) ? d0 : (Mt == 1) ? d1 : (Mt == 2) ? d2 : d3;
            #pragma unroll
            for (int r = 0; r < 4; ++r) {
                const float hv = softplus_f(fmaf(dd[r], IS32_3, w.b1v[Nt]));
                const int row = 16 * Mt + 4 * g + r;
                *(__half*)(slice + row * 144 + hcol * 2) = __float2half(hv);
            }
        }
    }

    f16x8 a2[4][2];
    #pragma unroll
    for (int Mt = 0; Mt < 4; ++Mt)
        #pragma unroll
        for (int kh = 0; kh < 2; ++kh)
            a2[Mt][kh] = *(const f16x8*)(slice + (16 * Mt + ln) * 144 + (kh * 4 + g) * 16);

    #pragma unroll
    for (int Nt2 = 0; Nt2 < 3; ++Nt2) {
        f32x4 e0 = {0.f, 0.f, 0.f, 0.f};
        f32x4 e1 = {0.f, 0.f, 0.f, 0.f};
        f32x4 e2 = {0.f, 0.f, 0.f, 0.f};
        f32x4 e3 = {0.f, 0.f, 0.f, 0.f};
        #pragma unroll
        for (int kh = 0; kh < 2; ++kh) {
            e0 = __builtin_amdgcn_mfma_f32_16x16x32_f16(a2[0][kh], w.b2f[Nt2][kh], e0, 0, 0, 0);
            e1 = __builtin_amdgcn_mfma_f32_16x16x32_f16(a2[1][kh], w.b2f[Nt2][kh], e1, 0, 0, 0);
            e2 = __builtin_amdgcn_mfma_f32_16x16x32_f16(a2[2][kh], w.b2f[Nt2][kh], e2, 0, 0, 0);
            e3 = __builtin_amdgcn_mfma_f32_16x16x32_f16(a2[3][kh], w.b2f[Nt2][kh], e3, 0, 0, 0);
        }
        const int o = 16 * Nt2 + ln;
        if (o == 0) {
            #pragma unroll
            for (int Mt = 0; Mt < 4; ++Mt) {
                f32x4 ee = (Mt == 0) ? e0 : (Mt == 1) ? e1 : (Mt == 2) ? e2 : e3;
                #pragma unroll
                for (int r = 0; r < 4; ++r) {
                    const int row = 16 * Mt + 4 * g + r;
                    *(float*)(slice + SIG_OFF + row * 4) = fmaf(ee[r], 0.125f, w.b2v[0]);
                }
            }
        } else if (o < 33) {
            #pragma unroll
            for (int Mt = 0; Mt < 4; ++Mt) {
                f32x4 ee = (Mt == 0) ? e0 : (Mt == 1) ? e1 : (Mt == 2) ? e2 : e3;
                #pragma unroll
                for (int r = 0; r < 4; ++r) {
                    const float vv = fmaf(ee[r], 0.125f, w.b2v[Nt2]);
                    const float rr = sigmoid_f(vv) * 1.002f - 0.001f;
                    const int row = 16 * Mt + 4 * g + r;
                    *(__half*)(slice + row * 80 + (o - 1) * 2) = __float2half(rr);
                }
            }
        }
    }
}

__global__ __launch_bounds__(THREADS)
void k_fused(const float* __restrict__ planes,
             const float* __restrict__ coords, const float* __restrict__ depths,
             const float* __restrict__ w1, const float* __restrict__ b1,
             const float* __restrict__ w2, const float* __restrict__ b2,
             float* __restrict__ out)
{
    __shared__ __align__(16) char sm[6 * SLICE];
    const int t = threadIdx.x;
    const int wv = t >> 6;
    const int l = t & 63;
    const int g = l >> 4;
    const int ln = l & 15;
    char* const slice = sm + wv * SLICE;

    const int msamp = blockIdx.x * THREADS + t;
    const int nb = (msamp >= M_TOTAL / NB) ? 1 : 0;

    Wreg w;
    load_weights(w, w1, b1, w2, b2, g, ln);

    const float* cp = coords + (size_t)msamp * 3;
    const float c0 = cp[0], c1 = cp[1], c2v = cp[2];
    const float myDep = depths[msamp];

    float xf32[CF];
    #pragma unroll
    for (int c = 0; c < CF; ++c) xf32[c] = 0.f;

    #pragma unroll
    for (int p = 0; p < 3; ++p) {
        const float u = (p == 2) ? c2v : c0;
        const float v = (p == 0) ? c1 : ((p == 1) ? c2v : c0);
        const float xf = fmaf(u, 128.f, 127.5f);
        const float yf = fmaf(v, 128.f, 127.5f);
        const float x0f = floorf(xf), y0f = floorf(yf);
        const float wx = xf - x0f, wy = yf - y0f;
        const int x0 = (int)x0f, y0 = (int)y0f;
        const float vx0 = (x0 >= 0 && x0 < HW) ? 1.f : 0.f;
        const float vx1 = (x0 + 1 >= 0 && x0 + 1 < HW) ? 1.f : 0.f;
        const float vy0 = (y0 >= 0 && y0 < HW) ? 1.f : 0.f;
        const float vy1 = (y0 + 1 >= 0 && y0 + 1 < HW) ? 1.f : 0.f;
        const int xc0 = min(max(x0, 0), HW - 1), xc1 = min(max(x0 + 1, 0), HW - 1);
        const int yc0 = min(max(y0, 0), HW - 1), yc1 = min(max(y0 + 1, 0), HW - 1);
        const float w00 = (1.f - wx) * (1.f - wy) * vx0 * vy0;
        const float w10 = wx * (1.f - wy) * vx1 * vy0;
        const float w01 = (1.f - wx) * wy * vx0 * vy1;
        const float w11 = wx * wy * vx1 * vy1;

        const float* pb = planes + (((size_t)(nb * 3 + p) * CF) << 16);
        const int i00 = yc0 * HW + xc0, i10 = yc0 * HW + xc1;
        const int i01 = yc1 * HW + xc0, i11 = yc1 * HW + xc1;
        #pragma unroll
        for (int c = 0; c < CF; ++c) {
            const float* pc = pb + ((size_t)c << 16);
            float a0 = fmaf(w00, pc[i00], fmaf(w10, pc[i10], 0.f));
            float a1v = fmaf(w01, pc[i01], fmaf(w11, pc[i11], 0.f));
            xf32[c] += a0 + a1v;
        }
    }

    #pragma unroll
    for (int c = 0; c < 4; ++c) {
        union { __half2 h[4]; i32x4 v; } u4;
        #pragma unroll
        for (int j = 0; j < 4; ++j)
            u4.h[j] = __floats2half2_rn(xf32[8 * c + 2 * j], xf32[8 * c + 2 * j + 1]);
        *(i32x4*)(slice + l * 80 + c * 16) = u4.v;
    }

    f16x8 a1[4];
    #pragma unroll
    for (int Mt = 0; Mt < 4; ++Mt)
        a1[Mt] = *(const f16x8*)(slice + (16 * Mt + ln) * 80 + g * 16);

    mlp_slice(slice, a1, w, g, ln);
    *(float*)(slice + DEP_OFF + l * 4) = myDep;

    __syncthreads();

    if (t < 128) {
        const int crl = t >> 5;
        const int c = t & 31;
        const int bs = crl * SAMP;
        auto sigAt = [&](int sb) -> float {
            return *(const float*)(sm + (sb >> 6) * SLICE + SIG_OFF + (sb & 63) * 4);
        };
        auto depAt = [&](int sb) -> float {
            return *(const float*)(sm + (sb >> 6) * SLICE + DEP_OFF + (sb & 63) * 4);
        };
        auto rgbAt = [&](int sb) -> float {
            return __half2float(*(const __half*)(sm + (sb >> 6) * SLICE + (sb & 63) * 80 + c * 2));
        };
        float T = 1.f, a_out = 0.f;
        float sp = sigAt(bs), dp = depAt(bs), rp = rgbAt(bs);
        for (int ss = 1; ss < SAMP; ++ss) {
            const float sc = sigAt(bs + ss);
            const float dc = depAt(bs + ss);
            const float rc = rgbAt(bs + ss);
            const float dens = softplus_f(0.5f * (sp + sc) - 1.f);
            const float alpha = 1.f - __expf(-(dc - dp) * dens);
            a_out = fmaf(alpha * T, 0.5f * (rp + rc), a_out);
            T *= 1.f - alpha + 1e-10f;
            sp = sc; dp = dc; rp = rc;
        }
        out[(size_t)(blockIdx.x * 4 + crl) * CF + c] = fmaf(a_out, 2.f, -1.f);
    }
}

extern "C" void kernel_launch(void* const* d_in, const int* in_sizes, int n_in,
                              void* d_out, int out_size, void* d_ws, size_t ws_size,
                              hipStream_t stream) {
    (void)in_sizes; (void)n_in; (void)out_size;
    const float* planes = (const float*)d_in[0];
    const float* coords = (const float*)d_in[1];
    const float* depths = (const float*)d_in[2];
    const float* w1 = (const float*)d_in[3];
    const float* b1 = (const float*)d_in[4];
    const float* w2 = (const float*)d_in[5];
    const float* b2 = (const float*)d_in[6];
    float* out = (float*)d_out;

    const size_t ptBytes = (size_t)NB * 3 * PTEX * CF * sizeof(__half);   // 25.56 MB
    dim3 tgrid((PTEX + 255) / 256, NB * 3);   // (261, 6)

    if (ws_size >= ptBytes) {
        __half2* pt = (__half2*)d_ws;
        k_transposeB<<<tgrid, 256, 0, stream>>>(planes, pt);
        k_rayC<<<NB * RAYS / 2, 128, 0, stream>>>(pt, coords, depths,
                                                  w1, b1, w2, b2, out);
    } else {
        k_fused<<<M_TOTAL / THREADS, THREADS, 0, stream>>>(planes, coords, depths,
                                                           w1, b1, w2, b2, out);
    }
}

// Round 11
// 172.210 us; speedup vs baseline: 1.1296x; 1.1296x over previous
//
#include <hip/hip_runtime.h>
#include <hip/hip_fp16.h>

#define NB 2
#define RAYS 4096
#define SAMP 96
#define CF 32
#define HID 64
#define HW 256
#define PW 258                  // padded plane width (1-texel zero border)
#define PTEX (PW * PW)          // 66564 texels per plane

constexpr int M_TOTAL = NB * RAYS * SAMP;   // 786432 samples

typedef _Float16 f16x8 __attribute__((ext_vector_type(8)));
typedef float f32x4 __attribute__((ext_vector_type(4)));
typedef int i32x4 __attribute__((ext_vector_type(4)));

__device__ __forceinline__ float softplus_f(float z) {
    return fmaxf(z, 0.f) + __logf(1.f + __expf(-fabsf(z)));
}
__device__ __forceinline__ float sigmoid_f(float z) {
    return __fdividef(1.f, 1.f + __expf(-z));
}

// planes (N,3,C,256,256) f32 -> pt (N*3, 258, 258, C) f16, zero border.
__global__ __launch_bounds__(256)
void k_transposeB(const float* __restrict__ src, __half2* __restrict__ dst) {
    const int xy = blockIdx.x * 256 + threadIdx.x;
    const int pn = blockIdx.y;                    // n*3+p in [0,6)
    if (xy >= PTEX) return;
    const int y = xy / PW;
    const int x = xy - y * PW;
    __half2 v[16];
    if (x >= 1 && x <= HW && y >= 1 && y <= HW) {
        const float* s = src + (((size_t)pn * CF) << 16) + (y - 1) * HW + (x - 1);
        #pragma unroll
        for (int c2 = 0; c2 < 16; ++c2) {
            const float a = s[((size_t)(2 * c2)) << 16];
            const float b = s[((size_t)(2 * c2 + 1)) << 16];
            v[c2] = __floats2half2_rn(a, b);
        }
    } else {
        #pragma unroll
        for (int c2 = 0; c2 < 16; ++c2) v[c2] = __float2half2_rn(0.f);
    }
    __half2* d = dst + ((size_t)pn * PTEX + xy) * 16;
    #pragma unroll
    for (int q = 0; q < 4; ++q)
        ((i32x4*)d)[q] = ((const i32x4*)v)[q];
}

// ---- shared device pieces ----
struct Wreg {
    f16x8 b1f[4];  float b1v[4];
    f16x8 b2f[3][2]; float b2v[3];
};

__device__ __forceinline__ void load_weights(Wreg& w,
        const float* __restrict__ w1, const float* __restrict__ b1,
        const float* __restrict__ w2, const float* __restrict__ b2,
        int g, int ln) {
    #pragma unroll
    for (int Nt = 0; Nt < 4; ++Nt) {
        const int hn = 16 * Nt + ln;
        const float4* p0 = (const float4*)(w1 + hn * CF + g * 8);
        float4 u = p0[0], v = p0[1];
        w.b1f[Nt][0] = (_Float16)u.x; w.b1f[Nt][1] = (_Float16)u.y;
        w.b1f[Nt][2] = (_Float16)u.z; w.b1f[Nt][3] = (_Float16)u.w;
        w.b1f[Nt][4] = (_Float16)v.x; w.b1f[Nt][5] = (_Float16)v.y;
        w.b1f[Nt][6] = (_Float16)v.z; w.b1f[Nt][7] = (_Float16)v.w;
        w.b1v[Nt] = b1[hn];
    }
    #pragma unroll
    for (int Nt2 = 0; Nt2 < 3; ++Nt2) {
        const int o = 16 * Nt2 + ln;
        if (o < 33) {
            #pragma unroll
            for (int kh = 0; kh < 2; ++kh) {
                const float4* p0 = (const float4*)(w2 + o * HID + kh * 32 + g * 8);
                float4 u = p0[0], v = p0[1];
                w.b2f[Nt2][kh][0] = (_Float16)u.x; w.b2f[Nt2][kh][1] = (_Float16)u.y;
                w.b2f[Nt2][kh][2] = (_Float16)u.z; w.b2f[Nt2][kh][3] = (_Float16)u.w;
                w.b2f[Nt2][kh][4] = (_Float16)v.x; w.b2f[Nt2][kh][5] = (_Float16)v.y;
                w.b2f[Nt2][kh][6] = (_Float16)v.z; w.b2f[Nt2][kh][7] = (_Float16)v.w;
            }
            w.b2v[Nt2] = b2[o];
        } else {
            #pragma unroll
            for (int kh = 0; kh < 2; ++kh)
                #pragma unroll
                for (int i = 0; i < 8; ++i) w.b2f[Nt2][kh][i] = (_Float16)0.f;
            w.b2v[Nt2] = 0.f;
        }
    }
}

// 4-lane cooperative gather vs the padded table: no masks/clamps (r9),
// 64B line shared by lanes g=0..3 (r7: 4x fewer TA line-probes).
__device__ __forceinline__ f16x8 gather4(const __half* __restrict__ ptb,
                                         float c0, float c1, float c2v, int g) {
    __half2 acc4[4];
    #pragma unroll
    for (int j = 0; j < 4; ++j) acc4[j] = __float2half2_rn(0.f);

    #pragma unroll
    for (int p = 0; p < 3; ++p) {
        const float u = (p == 2) ? c2v : c0;
        const float v = (p == 0) ? c1 : ((p == 1) ? c2v : c0);
        const float xf = fmaf(u, 128.f, 127.5f);
        const float yf = fmaf(v, 128.f, 127.5f);
        const float x0f = floorf(xf), y0f = floorf(yf);
        const float wx = xf - x0f, wy = yf - y0f;
        const int x0 = (int)x0f, y0 = (int)y0f;        // in [-1, 255]
        const int base = (y0 + 1) * PW + (x0 + 1);      // border handles OOB
        const __half* tp = ptb + (size_t)p * (PTEX * CF) + (size_t)base * CF + g * 8;
        const float w00 = (1.f - wx) * (1.f - wy);
        const float w10 = wx * (1.f - wy);
        const float w01 = (1.f - wx) * wy;
        const float w11 = wx * wy;
        auto tapf = [&](const __half* q, float w) {
            union { float4 f; __half2 h[4]; } u4;
            u4.f = *(const float4*)q;
            const __half2 wh = __float2half2_rn(w);
            acc4[0] = __hfma2(wh, u4.h[0], acc4[0]);
            acc4[1] = __hfma2(wh, u4.h[1], acc4[1]);
            acc4[2] = __hfma2(wh, u4.h[2], acc4[2]);
            acc4[3] = __hfma2(wh, u4.h[3], acc4[3]);
        };
        tapf(tp, w00);
        tapf(tp + CF, w10);
        tapf(tp + PW * CF, w01);
        tapf(tp + PW * CF + CF, w11);
    }
    union { __half2 h[4]; f16x8 f; } uf;
    #pragma unroll
    for (int j = 0; j < 4; ++j) uf.h[j] = acc4[j];
    return uf.f;     // raw sum; 1/3 folded into layer-1 scale
}

constexpr float IS32_3 = 0.058925565098879624f;   // (1/sqrt(32)) / 3

// ============== split path: gather+MLP (r9 structure + 2 new levers) ==============
// Lever 1 (L2): XCD-partitioned batches. Blocks dispatch round-robin over 8
//   XCDs (bid%8); give XCDs 0-3 only batch-0 samples and XCDs 4-7 batch-1 ->
//   each 4MB L2 serves a 12.8MB table instead of 25.6MB.
// Lever 2 (occupancy): w2 fragments live in a per-block LDS stash instead of
//   27 VGPRs held across the whole gather (r5/r6: occupancy tracks VGPR;
//   r5's forced-64 spilled BECAUSE b2f was resident. Now the natural peak
//   should drop toward 64 without spills). Both waves write identical stash
//   data (benign); each wave reads only after its own in-order writes -> no
//   barrier needed.
constexpr int TG = 128;
constexpr int SLICE_A = 9216;   // per-wave LDS slice bytes
constexpr int SIGO = 5120;      // sigma region (float[64])
constexpr int WSTASH = 112;     // per-lane: 48 halfs b2f + 3 floats b2v + pad

__global__ __launch_bounds__(TG)
void k_gmlpB(const __half2* __restrict__ pt, const float* __restrict__ coords,
             const float* __restrict__ w1, const float* __restrict__ b1,
             const float* __restrict__ w2, const float* __restrict__ b2,
             __half* __restrict__ rgbW, float* __restrict__ sigW)
{
    __shared__ __align__(16) char sm[2 * SLICE_A + 64 * WSTASH];   // 25.6 KB
    const int t = threadIdx.x;
    const int wv = t >> 6;
    const int l = t & 63;
    const int g = l >> 4;
    const int ln = l & 15;
    char* const slice = sm + wv * SLICE_A;
    char* const wbase = sm + 2 * SLICE_A + l * WSTASH;

    // ---- stash w2 fragments in LDS (regs die before gather) ----
    #pragma unroll
    for (int Nt2 = 0; Nt2 < 3; ++Nt2) {
        const int o = 16 * Nt2 + ln;
        #pragma unroll
        for (int kh = 0; kh < 2; ++kh) {
            f16x8 f;
            if (o < 33) {
                const float4* p0 = (const float4*)(w2 + o * HID + kh * 32 + g * 8);
                float4 u = p0[0], v = p0[1];
                f[0] = (_Float16)u.x; f[1] = (_Float16)u.y;
                f[2] = (_Float16)u.z; f[3] = (_Float16)u.w;
                f[4] = (_Float16)v.x; f[5] = (_Float16)v.y;
                f[6] = (_Float16)v.z; f[7] = (_Float16)v.w;
            } else {
                #pragma unroll
                for (int i = 0; i < 8; ++i) f[i] = (_Float16)0.f;
            }
            *(f16x8*)(wbase + (Nt2 * 2 + kh) * 16) = f;
        }
        *(float*)(wbase + 96 + Nt2 * 4) = (o < 33) ? b2[o] : 0.f;
    }

    // ---- w1 fragments in registers (needed right after gather) ----
    f16x8 b1f[4];
    float b1v[4];
    #pragma unroll
    for (int Nt = 0; Nt < 4; ++Nt) {
        const int hn = 16 * Nt + ln;
        const float4* p0 = (const float4*)(w1 + hn * CF + g * 8);
        float4 u = p0[0], v = p0[1];
        b1f[Nt][0] = (_Float16)u.x; b1f[Nt][1] = (_Float16)u.y;
        b1f[Nt][2] = (_Float16)u.z; b1f[Nt][3] = (_Float16)u.w;
        b1f[Nt][4] = (_Float16)v.x; b1f[Nt][5] = (_Float16)v.y;
        b1f[Nt][6] = (_Float16)v.z; b1f[Nt][7] = (_Float16)v.w;
        b1v[Nt] = b1[hn];
    }

    // ---- XCD-partitioned block->sample mapping ----
    const int bid = blockIdx.x;                 // 6144 = 768 * 8
    const int xcd = bid & 7;
    const int nb = xcd >> 2;                    // XCDs 0-3: batch 0; 4-7: batch 1
    const int rank = (bid >> 3) * 4 + (xcd & 3);   // 0..3071 within batch
    const int waveBaseS = nb * (M_TOTAL / NB) + rank * TG + wv * 64;
    const __half* ptb = (const __half*)pt + (size_t)nb * 3 * (PTEX * CF);

    // ---- coords prefetch (4 independent triples) ----
    float cx[4], cy[4], cz[4];
    #pragma unroll
    for (int Mt = 0; Mt < 4; ++Mt) {
        const float* cp = coords + (size_t)(waveBaseS + 16 * Mt + ln) * 3;
        cx[Mt] = cp[0]; cy[Mt] = cp[1]; cz[Mt] = cp[2];
    }

    // ---- gather: 4-lane-coalesced taps, A-fragments in registers ----
    f16x8 a1[4];
    #pragma unroll
    for (int Mt = 0; Mt < 4; ++Mt)
        a1[Mt] = gather4(ptb, cx[Mt], cy[Mt], cz[Mt], g);

    // ---- layer 1 via MFMA -> h in LDS ----
    #pragma unroll
    for (int Nt = 0; Nt < 4; ++Nt) {
        f32x4 d0 = {0.f, 0.f, 0.f, 0.f};
        f32x4 d1 = {0.f, 0.f, 0.f, 0.f};
        f32x4 d2 = {0.f, 0.f, 0.f, 0.f};
        f32x4 d3 = {0.f, 0.f, 0.f, 0.f};
        d0 = __builtin_amdgcn_mfma_f32_16x16x32_f16(a1[0], b1f[Nt], d0, 0, 0, 0);
        d1 = __builtin_amdgcn_mfma_f32_16x16x32_f16(a1[1], b1f[Nt], d1, 0, 0, 0);
        d2 = __builtin_amdgcn_mfma_f32_16x16x32_f16(a1[2], b1f[Nt], d2, 0, 0, 0);
        d3 = __builtin_amdgcn_mfma_f32_16x16x32_f16(a1[3], b1f[Nt], d3, 0, 0, 0);
        const int hcol = 16 * Nt + ln;
        #pragma unroll
        for (int Mt = 0; Mt < 4; ++Mt) {
            f32x4 dd = (Mt == 0) ? d0 : (Mt == 1) ? d1 : (Mt == 2) ? d2 : d3;
            #pragma unroll
            for (int r = 0; r < 4; ++r) {
                const float hv = softplus_f(fmaf(dd[r], IS32_3, b1v[Nt]));
                const int row = 16 * Mt + 4 * g + r;
                *(__half*)(slice + row * 144 + hcol * 2) = __float2half(hv);
            }
        }
    }

    // ---- layer-2 A-fragments (h transposed via LDS) ----
    f16x8 a2[4][2];
    #pragma unroll
    for (int Mt = 0; Mt < 4; ++Mt)
        #pragma unroll
        for (int kh = 0; kh < 2; ++kh)
            a2[Mt][kh] = *(const f16x8*)(slice + (16 * Mt + ln) * 144 + (kh * 4 + g) * 16);

    // ---- layer 2 via MFMA, w2 frags streamed from the LDS stash ----
    #pragma unroll
    for (int Nt2 = 0; Nt2 < 3; ++Nt2) {
        const f16x8 f0 = *(const f16x8*)(wbase + (Nt2 * 2 + 0) * 16);
        const f16x8 f1 = *(const f16x8*)(wbase + (Nt2 * 2 + 1) * 16);
        const float bv = *(const float*)(wbase + 96 + Nt2 * 4);
        f32x4 e0 = {0.f, 0.f, 0.f, 0.f};
        f32x4 e1 = {0.f, 0.f, 0.f, 0.f};
        f32x4 e2 = {0.f, 0.f, 0.f, 0.f};
        f32x4 e3 = {0.f, 0.f, 0.f, 0.f};
        e0 = __builtin_amdgcn_mfma_f32_16x16x32_f16(a2[0][0], f0, e0, 0, 0, 0);
        e1 = __builtin_amdgcn_mfma_f32_16x16x32_f16(a2[1][0], f0, e1, 0, 0, 0);
        e2 = __builtin_amdgcn_mfma_f32_16x16x32_f16(a2[2][0], f0, e2, 0, 0, 0);
        e3 = __builtin_amdgcn_mfma_f32_16x16x32_f16(a2[3][0], f0, e3, 0, 0, 0);
        e0 = __builtin_amdgcn_mfma_f32_16x16x32_f16(a2[0][1], f1, e0, 0, 0, 0);
        e1 = __builtin_amdgcn_mfma_f32_16x16x32_f16(a2[1][1], f1, e1, 0, 0, 0);
        e2 = __builtin_amdgcn_mfma_f32_16x16x32_f16(a2[2][1], f1, e2, 0, 0, 0);
        e3 = __builtin_amdgcn_mfma_f32_16x16x32_f16(a2[3][1], f1, e3, 0, 0, 0);
        const int o = 16 * Nt2 + ln;
        if (o == 0) {
            #pragma unroll
            for (int Mt = 0; Mt < 4; ++Mt) {
                f32x4 ee = (Mt == 0) ? e0 : (Mt == 1) ? e1 : (Mt == 2) ? e2 : e3;
                #pragma unroll
                for (int r = 0; r < 4; ++r) {
                    const int row = 16 * Mt + 4 * g + r;
                    *(float*)(slice + SIGO + row * 4) = fmaf(ee[r], 0.125f, bv);
                }
            }
        } else if (o < 33) {
            #pragma unroll
            for (int Mt = 0; Mt < 4; ++Mt) {
                f32x4 ee = (Mt == 0) ? e0 : (Mt == 1) ? e1 : (Mt == 2) ? e2 : e3;
                #pragma unroll
                for (int r = 0; r < 4; ++r) {
                    const float vv = fmaf(ee[r], 0.125f, bv);
                    const float rr = sigmoid_f(vv) * 1.002f - 0.001f;
                    const int row = 16 * Mt + 4 * g + r;
                    *(__half*)(slice + row * 80 + (o - 1) * 2) = __float2half(rr);
                }
            }
        }
    }

    // ---- coalesced nontemporal stores of rgb + sigma ----
    const int q0 = l & 3, r0 = l >> 2;
    #pragma unroll
    for (int q = 0; q < 4; ++q) {
        const int row = 16 * q + r0;
        i32x4 v = *(const i32x4*)(slice + row * 80 + q0 * 16);
        __builtin_nontemporal_store(v,
            (i32x4*)((char*)rgbW + (size_t)(waveBaseS + row) * 64 + q0 * 16));
    }
    const float sv = *(const float*)(slice + SIGO + l * 4);
    __builtin_nontemporal_store(sv, sigW + waveBaseS + l);
}

// ============== split path: composite ==============
__global__ __launch_bounds__(512)
void k_comp(const __half* __restrict__ rgbW, const float* __restrict__ sigW,
            const float* __restrict__ depths, float* __restrict__ out)
{
    __shared__ float sgS[16 * SAMP];
    __shared__ float dpS[16 * SAMP];
    const int t = threadIdx.x;
    const int rayBase = blockIdx.x * 16;
    for (int i = t; i < 16 * SAMP; i += 512) {
        sgS[i] = sigW[(size_t)rayBase * SAMP + i];
        dpS[i] = depths[(size_t)rayBase * SAMP + i];
    }
    __syncthreads();

    const int rs = t >> 5;
    const int c = t & 31;
    const size_t mb = (size_t)(rayBase + rs) * SAMP;
    const ushort* rgbU = (const ushort*)rgbW;

    auto ldr = [&](size_t idx) -> float {
        ushort u = __builtin_nontemporal_load(rgbU + idx);
        __half h = *(__half*)&u;
        return __half2float(h);
    };

    float T = 1.f, a_out = 0.f;
    float sp = sgS[rs * SAMP], dp = dpS[rs * SAMP];
    float rp = ldr(mb * 32 + c);
    float rnx = ldr((mb + 1) * 32 + c);
    #pragma unroll 2
    for (int ss = 1; ss < SAMP; ++ss) {
        const float rc = rnx;
        const int nxt = (ss + 1 < SAMP) ? (ss + 1) : (SAMP - 1);
        rnx = ldr((mb + nxt) * 32 + c);
        const float sc = sgS[rs * SAMP + ss];
        const float dc = dpS[rs * SAMP + ss];
        const float dens = softplus_f(0.5f * (sp + sc) - 1.f);
        const float alpha = 1.f - __expf(-(dc - dp) * dens);
        a_out = fmaf(alpha * T, 0.5f * (rp + rc), a_out);
        T *= 1.f - alpha + 1e-10f;
        sp = sc; dp = dc; rp = rc;
    }
    out[(size_t)(rayBase + rs) * CF + c] = fmaf(a_out, 2.f, -1.f);
}

// ============== fallback: direct from planes (no workspace) ==============
constexpr int THREADS = 384;
constexpr int SLICE = 9216;
constexpr int SIG_OFF = 5120;
constexpr int DEP_OFF = 5376;

__device__ __forceinline__ void mlp_slice(char* slice, const f16x8 a1[4],
                                          const Wreg& w, int g, int ln) {
    #pragma unroll
    for (int Nt = 0; Nt < 4; ++Nt) {
        f32x4 d0 = {0.f, 0.f, 0.f, 0.f};
        f32x4 d1 = {0.f, 0.f, 0.f, 0.f};
        f32x4 d2 = {0.f, 0.f, 0.f, 0.f};
        f32x4 d3 = {0.f, 0.f, 0.f, 0.f};
        d0 = __builtin_amdgcn_mfma_f32_16x16x32_f16(a1[0], w.b1f[Nt], d0, 0, 0, 0);
        d1 = __builtin_amdgcn_mfma_f32_16x16x32_f16(a1[1], w.b1f[Nt], d1, 0, 0, 0);
        d2 = __builtin_amdgcn_mfma_f32_16x16x32_f16(a1[2], w.b1f[Nt], d2, 0, 0, 0);
        d3 = __builtin_amdgcn_mfma_f32_16x16x32_f16(a1[3], w.b1f[Nt], d3, 0, 0, 0);
        const int hcol = 16 * Nt + ln;
        #pragma unroll
        for (int Mt = 0; Mt < 4; ++Mt) {
            f32x4 dd = (Mt == 0) ? d0 : (Mt == 1) ? d1 : (Mt == 2) ? d2 : d3;
            #pragma unroll
            for (int r = 0; r < 4; ++r) {
                const float hv = softplus_f(fmaf(dd[r], IS32_3, w.b1v[Nt]));
                const int row = 16 * Mt + 4 * g + r;
                *(__half*)(slice + row * 144 + hcol * 2) = __float2half(hv);
            }
        }
    }

    f16x8 a2[4][2];
    #pragma unroll
    for (int Mt = 0; Mt < 4; ++Mt)
        #pragma unroll
        for (int kh = 0; kh < 2; ++kh)
            a2[Mt][kh] = *(const f16x8*)(slice + (16 * Mt + ln) * 144 + (kh * 4 + g) * 16);

    #pragma unroll
    for (int Nt2 = 0; Nt2 < 3; ++Nt2) {
        f32x4 e0 = {0.f, 0.f, 0.f, 0.f};
        f32x4 e1 = {0.f, 0.f, 0.f, 0.f};
        f32x4 e2 = {0.f, 0.f, 0.f, 0.f};
        f32x4 e3 = {0.f, 0.f, 0.f, 0.f};
        #pragma unroll
        for (int kh = 0; kh < 2; ++kh) {
            e0 = __builtin_amdgcn_mfma_f32_16x16x32_f16(a2[0][kh], w.b2f[Nt2][kh], e0, 0, 0, 0);
            e1 = __builtin_amdgcn_mfma_f32_16x16x32_f16(a2[1][kh], w.b2f[Nt2][kh], e1, 0, 0, 0);
            e2 = __builtin_amdgcn_mfma_f32_16x16x32_f16(a2[2][kh], w.b2f[Nt2][kh], e2, 0, 0, 0);
            e3 = __builtin_amdgcn_mfma_f32_16x16x32_f16(a2[3][kh], w.b2f[Nt2][kh], e3, 0, 0, 0);
        }
        const int o = 16 * Nt2 + ln;
        if (o == 0) {
            #pragma unroll
            for (int Mt = 0; Mt < 4; ++Mt) {
                f32x4 ee = (Mt == 0) ? e0 : (Mt == 1) ? e1 : (Mt == 2) ? e2 : e3;
                #pragma unroll
                for (int r = 0; r < 4; ++r) {
                    const int row = 16 * Mt + 4 * g + r;
                    *(float*)(slice + SIG_OFF + row * 4) = fmaf(ee[r], 0.125f, w.b2v[0]);
                }
            }
        } else if (o < 33) {
            #pragma unroll
            for (int Mt = 0; Mt < 4; ++Mt) {
                f32x4 ee = (Mt == 0) ? e0 : (Mt == 1) ? e1 : (Mt == 2) ? e2 : e3;
                #pragma unroll
                for (int r = 0; r < 4; ++r) {
                    const float vv = fmaf(ee[r], 0.125f, w.b2v[Nt2]);
                    const float rr = sigmoid_f(vv) * 1.002f - 0.001f;
                    const int row = 16 * Mt + 4 * g + r;
                    *(__half*)(slice + row * 80 + (o - 1) * 2) = __float2half(rr);
                }
            }
        }
    }
}

__global__ __launch_bounds__(THREADS)
void k_fused(const float* __restrict__ planes,
             const float* __restrict__ coords, const float* __restrict__ depths,
             const float* __restrict__ w1, const float* __restrict__ b1,
             const float* __restrict__ w2, const float* __restrict__ b2,
             float* __restrict__ out)
{
    __shared__ __align__(16) char sm[6 * SLICE];
    const int t = threadIdx.x;
    const int wv = t >> 6;
    const int l = t & 63;
    const int g = l >> 4;
    const int ln = l & 15;
    char* const slice = sm + wv * SLICE;

    const int msamp = blockIdx.x * THREADS + t;
    const int nb = (msamp >= M_TOTAL / NB) ? 1 : 0;

    Wreg w;
    load_weights(w, w1, b1, w2, b2, g, ln);

    const float* cp = coords + (size_t)msamp * 3;
    const float c0 = cp[0], c1 = cp[1], c2v = cp[2];
    const float myDep = depths[msamp];

    float xf32[CF];
    #pragma unroll
    for (int c = 0; c < CF; ++c) xf32[c] = 0.f;

    #pragma unroll
    for (int p = 0; p < 3; ++p) {
        const float u = (p == 2) ? c2v : c0;
        const float v = (p == 0) ? c1 : ((p == 1) ? c2v : c0);
        const float xf = fmaf(u, 128.f, 127.5f);
        const float yf = fmaf(v, 128.f, 127.5f);
        const float x0f = floorf(xf), y0f = floorf(yf);
        const float wx = xf - x0f, wy = yf - y0f;
        const int x0 = (int)x0f, y0 = (int)y0f;
        const float vx0 = (x0 >= 0 && x0 < HW) ? 1.f : 0.f;
        const float vx1 = (x0 + 1 >= 0 && x0 + 1 < HW) ? 1.f : 0.f;
        const float vy0 = (y0 >= 0 && y0 < HW) ? 1.f : 0.f;
        const float vy1 = (y0 + 1 >= 0 && y0 + 1 < HW) ? 1.f : 0.f;
        const int xc0 = min(max(x0, 0), HW - 1), xc1 = min(max(x0 + 1, 0), HW - 1);
        const int yc0 = min(max(y0, 0), HW - 1), yc1 = min(max(y0 + 1, 0), HW - 1);
        const float w00 = (1.f - wx) * (1.f - wy) * vx0 * vy0;
        const float w10 = wx * (1.f - wy) * vx1 * vy0;
        const float w01 = (1.f - wx) * wy * vx0 * vy1;
        const float w11 = wx * wy * vx1 * vy1;

        const float* pb = planes + (((size_t)(nb * 3 + p) * CF) << 16);
        const int i00 = yc0 * HW + xc0, i10 = yc0 * HW + xc1;
        const int i01 = yc1 * HW + xc0, i11 = yc1 * HW + xc1;
        #pragma unroll
        for (int c = 0; c < CF; ++c) {
            const float* pc = pb + ((size_t)c << 16);
            float a0 = fmaf(w00, pc[i00], fmaf(w10, pc[i10], 0.f));
            float a1v = fmaf(w01, pc[i01], fmaf(w11, pc[i11], 0.f));
            xf32[c] += a0 + a1v;
        }
    }

    #pragma unroll
    for (int c = 0; c < 4; ++c) {
        union { __half2 h[4]; i32x4 v; } u4;
        #pragma unroll
        for (int j = 0; j < 4; ++j)
            u4.h[j] = __floats2half2_rn(xf32[8 * c + 2 * j], xf32[8 * c + 2 * j + 1]);
        *(i32x4*)(slice + l * 80 + c * 16) = u4.v;
    }

    f16x8 a1[4];
    #pragma unroll
    for (int Mt = 0; Mt < 4; ++Mt)
        a1[Mt] = *(const f16x8*)(slice + (16 * Mt + ln) * 80 + g * 16);

    mlp_slice(slice, a1, w, g, ln);
    *(float*)(slice + DEP_OFF + l * 4) = myDep;

    __syncthreads();

    if (t < 128) {
        const int crl = t >> 5;
        const int c = t & 31;
        const int bs = crl * SAMP;
        auto sigAt = [&](int sb) -> float {
            return *(const float*)(sm + (sb >> 6) * SLICE + SIG_OFF + (sb & 63) * 4);
        };
        auto depAt = [&](int sb) -> float {
            return *(const float*)(sm + (sb >> 6) * SLICE + DEP_OFF + (sb & 63) * 4);
        };
        auto rgbAt = [&](int sb) -> float {
            return __half2float(*(const __half*)(sm + (sb >> 6) * SLICE + (sb & 63) * 80 + c * 2));
        };
        float T = 1.f, a_out = 0.f;
        float sp = sigAt(bs), dp = depAt(bs), rp = rgbAt(bs);
        for (int ss = 1; ss < SAMP; ++ss) {
            const float sc = sigAt(bs + ss);
            const float dc = depAt(bs + ss);
            const float rc = rgbAt(bs + ss);
            const float dens = softplus_f(0.5f * (sp + sc) - 1.f);
            const float alpha = 1.f - __expf(-(dc - dp) * dens);
            a_out = fmaf(alpha * T, 0.5f * (rp + rc), a_out);
            T *= 1.f - alpha + 1e-10f;
            sp = sc; dp = dc; rp = rc;
        }
        out[(size_t)(blockIdx.x * 4 + crl) * CF + c] = fmaf(a_out, 2.f, -1.f);
    }
}

extern "C" void kernel_launch(void* const* d_in, const int* in_sizes, int n_in,
                              void* d_out, int out_size, void* d_ws, size_t ws_size,
                              hipStream_t stream) {
    (void)in_sizes; (void)n_in; (void)out_size;
    const float* planes = (const float*)d_in[0];
    const float* coords = (const float*)d_in[1];
    const float* depths = (const float*)d_in[2];
    const float* w1 = (const float*)d_in[3];
    const float* b1 = (const float*)d_in[4];
    const float* w2 = (const float*)d_in[5];
    const float* b2 = (const float*)d_in[6];
    float* out = (float*)d_out;

    const size_t ptBytes  = (size_t)NB * 3 * PTEX * CF * sizeof(__half);   // 25.56 MB
    const size_t rgbBytes = (size_t)M_TOTAL * CF * sizeof(__half);         // 50.33 MB
    const size_t sigBytes = (size_t)M_TOTAL * sizeof(float);               //  3.15 MB

    dim3 tgrid((PTEX + 255) / 256, NB * 3);   // (261, 6)

    if (ws_size >= ptBytes + rgbBytes + sigBytes) {
        __half2* pt = (__half2*)d_ws;
        __half* rgbW = (__half*)((char*)d_ws + ptBytes);
        float* sigW = (float*)((char*)d_ws + ptBytes + rgbBytes);
        k_transposeB<<<tgrid, 256, 0, stream>>>(planes, pt);
        k_gmlpB<<<M_TOTAL / TG, TG, 0, stream>>>(pt, coords, w1, b1, w2, b2, rgbW, sigW);
        k_comp<<<NB * RAYS / 16, 512, 0, stream>>>(rgbW, sigW, depths, out);
    } else {
        k_fused<<<M_TOTAL / THREADS, THREADS, 0, stream>>>(planes, coords, depths,
                                                           w1, b1, w2, b2, out);
    }
}

// Round 12
// 170.852 us; speedup vs baseline: 1.1386x; 1.0079x over previous
//
#include <hip/hip_runtime.h>
#include <hip/hip_fp16.h>

#define NB 2
#define RAYS 4096
#define SAMP 96
#define CF 32
#define HID 64
#define HW 256
#define PW 258                  // padded plane width (1-texel zero border)
#define PTEX (PW * PW)          // 66564 texels per plane

constexpr int M_TOTAL = NB * RAYS * SAMP;   // 786432 samples

typedef _Float16 f16x8 __attribute__((ext_vector_type(8)));
typedef float f32x4 __attribute__((ext_vector_type(4)));
typedef int i32x4 __attribute__((ext_vector_type(4)));

__device__ __forceinline__ float softplus_f(float z) {
    return fmaxf(z, 0.f) + __logf(1.f + __expf(-fabsf(z)));
}
__device__ __forceinline__ float sigmoid_f(float z) {
    return __fdividef(1.f, 1.f + __expf(-z));
}

// planes (N,3,C,256,256) f32 -> pt (N*3, 258, 258, C) f16, zero border.
__global__ __launch_bounds__(256)
void k_transposeB(const float* __restrict__ src, __half2* __restrict__ dst) {
    const int xy = blockIdx.x * 256 + threadIdx.x;
    const int pn = blockIdx.y;                    // n*3+p in [0,6)
    if (xy >= PTEX) return;
    const int y = xy / PW;
    const int x = xy - y * PW;
    __half2 v[16];
    if (x >= 1 && x <= HW && y >= 1 && y <= HW) {
        const float* s = src + (((size_t)pn * CF) << 16) + (y - 1) * HW + (x - 1);
        #pragma unroll
        for (int c2 = 0; c2 < 16; ++c2) {
            const float a = s[((size_t)(2 * c2)) << 16];
            const float b = s[((size_t)(2 * c2 + 1)) << 16];
            v[c2] = __floats2half2_rn(a, b);
        }
    } else {
        #pragma unroll
        for (int c2 = 0; c2 < 16; ++c2) v[c2] = __float2half2_rn(0.f);
    }
    __half2* d = dst + ((size_t)pn * PTEX + xy) * 16;
    #pragma unroll
    for (int q = 0; q < 4; ++q)
        ((i32x4*)d)[q] = ((const i32x4*)v)[q];
}

// ---- shared device pieces (fallback path) ----
struct Wreg {
    f16x8 b1f[4];  float b1v[4];
    f16x8 b2f[3][2]; float b2v[3];
};

__device__ __forceinline__ void load_weights(Wreg& w,
        const float* __restrict__ w1, const float* __restrict__ b1,
        const float* __restrict__ w2, const float* __restrict__ b2,
        int g, int ln) {
    #pragma unroll
    for (int Nt = 0; Nt < 4; ++Nt) {
        const int hn = 16 * Nt + ln;
        const float4* p0 = (const float4*)(w1 + hn * CF + g * 8);
        float4 u = p0[0], v = p0[1];
        w.b1f[Nt][0] = (_Float16)u.x; w.b1f[Nt][1] = (_Float16)u.y;
        w.b1f[Nt][2] = (_Float16)u.z; w.b1f[Nt][3] = (_Float16)u.w;
        w.b1f[Nt][4] = (_Float16)v.x; w.b1f[Nt][5] = (_Float16)v.y;
        w.b1f[Nt][6] = (_Float16)v.z; w.b1f[Nt][7] = (_Float16)v.w;
        w.b1v[Nt] = b1[hn];
    }
    #pragma unroll
    for (int Nt2 = 0; Nt2 < 3; ++Nt2) {
        const int o = 16 * Nt2 + ln;
        if (o < 33) {
            #pragma unroll
            for (int kh = 0; kh < 2; ++kh) {
                const float4* p0 = (const float4*)(w2 + o * HID + kh * 32 + g * 8);
                float4 u = p0[0], v = p0[1];
                w.b2f[Nt2][kh][0] = (_Float16)u.x; w.b2f[Nt2][kh][1] = (_Float16)u.y;
                w.b2f[Nt2][kh][2] = (_Float16)u.z; w.b2f[Nt2][kh][3] = (_Float16)u.w;
                w.b2f[Nt2][kh][4] = (_Float16)v.x; w.b2f[Nt2][kh][5] = (_Float16)v.y;
                w.b2f[Nt2][kh][6] = (_Float16)v.z; w.b2f[Nt2][kh][7] = (_Float16)v.w;
            }
            w.b2v[Nt2] = b2[o];
        } else {
            #pragma unroll
            for (int kh = 0; kh < 2; ++kh)
                #pragma unroll
                for (int i = 0; i < 8; ++i) w.b2f[Nt2][kh][i] = (_Float16)0.f;
            w.b2v[Nt2] = 0.f;
        }
    }
}

// 4-lane cooperative gather vs the padded table: no masks/clamps (r9),
// 64B line shared by lanes g=0..3 (r7: 4x fewer TA line-probes).
__device__ __forceinline__ f16x8 gather4(const __half* __restrict__ ptb,
                                         float c0, float c1, float c2v, int g) {
    __half2 acc4[4];
    #pragma unroll
    for (int j = 0; j < 4; ++j) acc4[j] = __float2half2_rn(0.f);

    #pragma unroll
    for (int p = 0; p < 3; ++p) {
        const float u = (p == 2) ? c2v : c0;
        const float v = (p == 0) ? c1 : ((p == 1) ? c2v : c0);
        const float xf = fmaf(u, 128.f, 127.5f);
        const float yf = fmaf(v, 128.f, 127.5f);
        const float x0f = floorf(xf), y0f = floorf(yf);
        const float wx = xf - x0f, wy = yf - y0f;
        const int x0 = (int)x0f, y0 = (int)y0f;        // in [-1, 255]
        const int base = (y0 + 1) * PW + (x0 + 1);      // border handles OOB
        const __half* tp = ptb + (size_t)p * (PTEX * CF) + (size_t)base * CF + g * 8;
        const float w00 = (1.f - wx) * (1.f - wy);
        const float w10 = wx * (1.f - wy);
        const float w01 = (1.f - wx) * wy;
        const float w11 = wx * wy;
        auto tapf = [&](const __half* q, float w) {
            union { float4 f; __half2 h[4]; } u4;
            u4.f = *(const float4*)q;
            const __half2 wh = __float2half2_rn(w);
            acc4[0] = __hfma2(wh, u4.h[0], acc4[0]);
            acc4[1] = __hfma2(wh, u4.h[1], acc4[1]);
            acc4[2] = __hfma2(wh, u4.h[2], acc4[2]);
            acc4[3] = __hfma2(wh, u4.h[3], acc4[3]);
        };
        tapf(tp, w00);
        tapf(tp + CF, w10);
        tapf(tp + PW * CF, w01);
        tapf(tp + PW * CF + CF, w11);
    }
    union { __half2 h[4]; f16x8 f; } uf;
    #pragma unroll
    for (int j = 0; j < 4; ++j) uf.h[j] = acc4[j];
    return uf.f;     // raw sum; 1/3 folded into layer-1 scale
}

constexpr float IS32_3 = 0.058925565098879624f;   // (1/sqrt(32)) / 3

// ============== split path: gather+MLP ==============
// r12: ALL weights deferred to use-time (w1 right before layer 1, w2 inside
// the layer-2 loop; both 8KB and L2-hot) with sched_barrier(0) fencing so the
// compiler can't hoist them into the gather region. Gather-phase live set =
// a1(16)+coords(12)+acc(8)+temps -> target ~60 VGPR. No LDS stash -> 18.4KB
// -> 8 blocks/CU. (r5/r9/r11: duration tracks resident waves tracks VGPR.)
constexpr int TG = 128;
constexpr int SLICE_A = 9216;   // per-wave LDS slice bytes
constexpr int SIGO = 5120;      // sigma region (float[64])

__global__ __launch_bounds__(TG)
void k_gmlpB(const __half2* __restrict__ pt, const float* __restrict__ coords,
             const float* __restrict__ w1, const float* __restrict__ b1,
             const float* __restrict__ w2, const float* __restrict__ b2,
             __half* __restrict__ rgbW, float* __restrict__ sigW)
{
    __shared__ __align__(16) char sm[2 * SLICE_A];   // 18.4 KB
    const int t = threadIdx.x;
    const int wv = t >> 6;
    const int l = t & 63;
    const int g = l >> 4;
    const int ln = l & 15;
    char* const slice = sm + wv * SLICE_A;

    // ---- XCD-partitioned block->sample mapping (r11) ----
    const int bid = blockIdx.x;                 // 6144 = 768 * 8
    const int xcd = bid & 7;
    const int nb = xcd >> 2;                    // XCDs 0-3: batch 0; 4-7: batch 1
    const int rank = (bid >> 3) * 4 + (xcd & 3);   // 0..3071 within batch
    const int waveBaseS = nb * (M_TOTAL / NB) + rank * TG + wv * 64;
    const __half* ptb = (const __half*)pt + (size_t)nb * 3 * (PTEX * CF);

    // ---- coords prefetch (4 independent triples; breaks Mt latency chain) ----
    float cx[4], cy[4], cz[4];
    #pragma unroll
    for (int Mt = 0; Mt < 4; ++Mt) {
        const float* cp = coords + (size_t)(waveBaseS + 16 * Mt + ln) * 3;
        cx[Mt] = cp[0]; cy[Mt] = cp[1]; cz[Mt] = cp[2];
    }

    // ---- gather: 4-lane-coalesced taps, A-fragments in registers ----
    f16x8 a1[4];
    #pragma unroll
    for (int Mt = 0; Mt < 4; ++Mt)
        a1[Mt] = gather4(ptb, cx[Mt], cy[Mt], cz[Mt], g);

    // fence: keep weight loads OUT of the gather region (live-range control)
    __builtin_amdgcn_sched_barrier(0);

    // ---- layer 1: load w1 fragments just-in-time, then MFMA -> h in LDS ----
    f16x8 b1f[4];
    float b1v[4];
    #pragma unroll
    for (int Nt = 0; Nt < 4; ++Nt) {
        const int hn = 16 * Nt + ln;
        const float4* p0 = (const float4*)(w1 + hn * CF + g * 8);
        float4 u = p0[0], v = p0[1];
        b1f[Nt][0] = (_Float16)u.x; b1f[Nt][1] = (_Float16)u.y;
        b1f[Nt][2] = (_Float16)u.z; b1f[Nt][3] = (_Float16)u.w;
        b1f[Nt][4] = (_Float16)v.x; b1f[Nt][5] = (_Float16)v.y;
        b1f[Nt][6] = (_Float16)v.z; b1f[Nt][7] = (_Float16)v.w;
        b1v[Nt] = b1[hn];
    }

    #pragma unroll
    for (int Nt = 0; Nt < 4; ++Nt) {
        f32x4 d0 = {0.f, 0.f, 0.f, 0.f};
        f32x4 d1 = {0.f, 0.f, 0.f, 0.f};
        f32x4 d2 = {0.f, 0.f, 0.f, 0.f};
        f32x4 d3 = {0.f, 0.f, 0.f, 0.f};
        d0 = __builtin_amdgcn_mfma_f32_16x16x32_f16(a1[0], b1f[Nt], d0, 0, 0, 0);
        d1 = __builtin_amdgcn_mfma_f32_16x16x32_f16(a1[1], b1f[Nt], d1, 0, 0, 0);
        d2 = __builtin_amdgcn_mfma_f32_16x16x32_f16(a1[2], b1f[Nt], d2, 0, 0, 0);
        d3 = __builtin_amdgcn_mfma_f32_16x16x32_f16(a1[3], b1f[Nt], d3, 0, 0, 0);
        const int hcol = 16 * Nt + ln;
        #pragma unroll
        for (int Mt = 0; Mt < 4; ++Mt) {
            f32x4 dd = (Mt == 0) ? d0 : (Mt == 1) ? d1 : (Mt == 2) ? d2 : d3;
            #pragma unroll
            for (int r = 0; r < 4; ++r) {
                const float hv = softplus_f(fmaf(dd[r], IS32_3, b1v[Nt]));
                const int row = 16 * Mt + 4 * g + r;
                *(__half*)(slice + row * 144 + hcol * 2) = __float2half(hv);
            }
        }
    }

    // ---- layer-2 A-fragments (h transposed via LDS) ----
    f16x8 a2[4][2];
    #pragma unroll
    for (int Mt = 0; Mt < 4; ++Mt)
        #pragma unroll
        for (int kh = 0; kh < 2; ++kh)
            a2[Mt][kh] = *(const f16x8*)(slice + (16 * Mt + ln) * 144 + (kh * 4 + g) * 16);

    // ---- layer 2: w2 fragments loaded just-in-time inside the loop ----
    #pragma unroll
    for (int Nt2 = 0; Nt2 < 3; ++Nt2) {
        const int o = 16 * Nt2 + ln;
        f16x8 f0, f1;
        float bv;
        if (o < 33) {
            const float4* p0 = (const float4*)(w2 + o * HID + g * 8);
            float4 u = p0[0], v = p0[1];
            f0[0] = (_Float16)u.x; f0[1] = (_Float16)u.y;
            f0[2] = (_Float16)u.z; f0[3] = (_Float16)u.w;
            f0[4] = (_Float16)v.x; f0[5] = (_Float16)v.y;
            f0[6] = (_Float16)v.z; f0[7] = (_Float16)v.w;
            const float4* p1 = (const float4*)(w2 + o * HID + 32 + g * 8);
            float4 u1 = p1[0], v1 = p1[1];
            f1[0] = (_Float16)u1.x; f1[1] = (_Float16)u1.y;
            f1[2] = (_Float16)u1.z; f1[3] = (_Float16)u1.w;
            f1[4] = (_Float16)v1.x; f1[5] = (_Float16)v1.y;
            f1[6] = (_Float16)v1.z; f1[7] = (_Float16)v1.w;
            bv = b2[o];
        } else {
            #pragma unroll
            for (int i = 0; i < 8; ++i) { f0[i] = (_Float16)0.f; f1[i] = (_Float16)0.f; }
            bv = 0.f;
        }
        f32x4 e0 = {0.f, 0.f, 0.f, 0.f};
        f32x4 e1 = {0.f, 0.f, 0.f, 0.f};
        f32x4 e2 = {0.f, 0.f, 0.f, 0.f};
        f32x4 e3 = {0.f, 0.f, 0.f, 0.f};
        e0 = __builtin_amdgcn_mfma_f32_16x16x32_f16(a2[0][0], f0, e0, 0, 0, 0);
        e1 = __builtin_amdgcn_mfma_f32_16x16x32_f16(a2[1][0], f0, e1, 0, 0, 0);
        e2 = __builtin_amdgcn_mfma_f32_16x16x32_f16(a2[2][0], f0, e2, 0, 0, 0);
        e3 = __builtin_amdgcn_mfma_f32_16x16x32_f16(a2[3][0], f0, e3, 0, 0, 0);
        e0 = __builtin_amdgcn_mfma_f32_16x16x32_f16(a2[0][1], f1, e0, 0, 0, 0);
        e1 = __builtin_amdgcn_mfma_f32_16x16x32_f16(a2[1][1], f1, e1, 0, 0, 0);
        e2 = __builtin_amdgcn_mfma_f32_16x16x32_f16(a2[2][1], f1, e2, 0, 0, 0);
        e3 = __builtin_amdgcn_mfma_f32_16x16x32_f16(a2[3][1], f1, e3, 0, 0, 0);
        if (o == 0) {
            #pragma unroll
            for (int Mt = 0; Mt < 4; ++Mt) {
                f32x4 ee = (Mt == 0) ? e0 : (Mt == 1) ? e1 : (Mt == 2) ? e2 : e3;
                #pragma unroll
                for (int r = 0; r < 4; ++r) {
                    const int row = 16 * Mt + 4 * g + r;
                    *(float*)(slice + SIGO + row * 4) = fmaf(ee[r], 0.125f, bv);
                }
            }
        } else if (o < 33) {
            #pragma unroll
            for (int Mt = 0; Mt < 4; ++Mt) {
                f32x4 ee = (Mt == 0) ? e0 : (Mt == 1) ? e1 : (Mt == 2) ? e2 : e3;
                #pragma unroll
                for (int r = 0; r < 4; ++r) {
                    const float vv = fmaf(ee[r], 0.125f, bv);
                    const float rr = sigmoid_f(vv) * 1.002f - 0.001f;
                    const int row = 16 * Mt + 4 * g + r;
                    *(__half*)(slice + row * 80 + (o - 1) * 2) = __float2half(rr);
                }
            }
        }
    }

    // ---- coalesced nontemporal stores of rgb + sigma ----
    const int q0 = l & 3, r0 = l >> 2;
    #pragma unroll
    for (int q = 0; q < 4; ++q) {
        const int row = 16 * q + r0;
        i32x4 v = *(const i32x4*)(slice + row * 80 + q0 * 16);
        __builtin_nontemporal_store(v,
            (i32x4*)((char*)rgbW + (size_t)(waveBaseS + row) * 64 + q0 * 16));
    }
    const float sv = *(const float*)(slice + SIGO + l * 4);
    __builtin_nontemporal_store(sv, sigW + waveBaseS + l);
}

// ============== split path: composite ==============
__global__ __launch_bounds__(512)
void k_comp(const __half* __restrict__ rgbW, const float* __restrict__ sigW,
            const float* __restrict__ depths, float* __restrict__ out)
{
    __shared__ float sgS[16 * SAMP];
    __shared__ float dpS[16 * SAMP];
    const int t = threadIdx.x;
    const int rayBase = blockIdx.x * 16;
    for (int i = t; i < 16 * SAMP; i += 512) {
        sgS[i] = sigW[(size_t)rayBase * SAMP + i];
        dpS[i] = depths[(size_t)rayBase * SAMP + i];
    }
    __syncthreads();

    const int rs = t >> 5;
    const int c = t & 31;
    const size_t mb = (size_t)(rayBase + rs) * SAMP;
    const ushort* rgbU = (const ushort*)rgbW;

    auto ldr = [&](size_t idx) -> float {
        ushort u = __builtin_nontemporal_load(rgbU + idx);
        __half h = *(__half*)&u;
        return __half2float(h);
    };

    float T = 1.f, a_out = 0.f;
    float sp = sgS[rs * SAMP], dp = dpS[rs * SAMP];
    float rp = ldr(mb * 32 + c);
    float rnx = ldr((mb + 1) * 32 + c);
    #pragma unroll 2
    for (int ss = 1; ss < SAMP; ++ss) {
        const float rc = rnx;
        const int nxt = (ss + 1 < SAMP) ? (ss + 1) : (SAMP - 1);
        rnx = ldr((mb + nxt) * 32 + c);
        const float sc = sgS[rs * SAMP + ss];
        const float dc = dpS[rs * SAMP + ss];
        const float dens = softplus_f(0.5f * (sp + sc) - 1.f);
        const float alpha = 1.f - __expf(-(dc - dp) * dens);
        a_out = fmaf(alpha * T, 0.5f * (rp + rc), a_out);
        T *= 1.f - alpha + 1e-10f;
        sp = sc; dp = dc; rp = rc;
    }
    out[(size_t)(rayBase + rs) * CF + c] = fmaf(a_out, 2.f, -1.f);
}

// ============== fallback: direct from planes (no workspace) ==============
constexpr int THREADS = 384;
constexpr int SLICE = 9216;
constexpr int SIG_OFF = 5120;
constexpr int DEP_OFF = 5376;

__device__ __forceinline__ void mlp_slice(char* slice, const f16x8 a1[4],
                                          const Wreg& w, int g, int ln) {
    #pragma unroll
    for (int Nt = 0; Nt < 4; ++Nt) {
        f32x4 d0 = {0.f, 0.f, 0.f, 0.f};
        f32x4 d1 = {0.f, 0.f, 0.f, 0.f};
        f32x4 d2 = {0.f, 0.f, 0.f, 0.f};
        f32x4 d3 = {0.f, 0.f, 0.f, 0.f};
        d0 = __builtin_amdgcn_mfma_f32_16x16x32_f16(a1[0], w.b1f[Nt], d0, 0, 0, 0);
        d1 = __builtin_amdgcn_mfma_f32_16x16x32_f16(a1[1], w.b1f[Nt], d1, 0, 0, 0);
        d2 = __builtin_amdgcn_mfma_f32_16x16x32_f16(a1[2], w.b1f[Nt], d2, 0, 0, 0);
        d3 = __builtin_amdgcn_mfma_f32_16x16x32_f16(a1[3], w.b1f[Nt], d3, 0, 0, 0);
        const int hcol = 16 * Nt + ln;
        #pragma unroll
        for (int Mt = 0; Mt < 4; ++Mt) {
            f32x4 dd = (Mt == 0) ? d0 : (Mt == 1) ? d1 : (Mt == 2) ? d2 : d3;
            #pragma unroll
            for (int r = 0; r < 4; ++r) {
                const float hv = softplus_f(fmaf(dd[r], IS32_3, w.b1v[Nt]));
                const int row = 16 * Mt + 4 * g + r;
                *(__half*)(slice + row * 144 + hcol * 2) = __float2half(hv);
            }
        }
    }

    f16x8 a2[4][2];
    #pragma unroll
    for (int Mt = 0; Mt < 4; ++Mt)
        #pragma unroll
        for (int kh = 0; kh < 2; ++kh)
            a2[Mt][kh] = *(const f16x8*)(slice + (16 * Mt + ln) * 144 + (kh * 4 + g) * 16);

    #pragma unroll
    for (int Nt2 = 0; Nt2 < 3; ++Nt2) {
        f32x4 e0 = {0.f, 0.f, 0.f, 0.f};
        f32x4 e1 = {0.f, 0.f, 0.f, 0.f};
        f32x4 e2 = {0.f, 0.f, 0.f, 0.f};
        f32x4 e3 = {0.f, 0.f, 0.f, 0.f};
        #pragma unroll
        for (int kh = 0; kh < 2; ++kh) {
            e0 = __builtin_amdgcn_mfma_f32_16x16x32_f16(a2[0][kh], w.b2f[Nt2][kh], e0, 0, 0, 0);
            e1 = __builtin_amdgcn_mfma_f32_16x16x32_f16(a2[1][kh], w.b2f[Nt2][kh], e1, 0, 0, 0);
            e2 = __builtin_amdgcn_mfma_f32_16x16x32_f16(a2[2][kh], w.b2f[Nt2][kh], e2, 0, 0, 0);
            e3 = __builtin_amdgcn_mfma_f32_16x16x32_f16(a2[3][kh], w.b2f[Nt2][kh], e3, 0, 0, 0);
        }
        const int o = 16 * Nt2 + ln;
        if (o == 0) {
            #pragma unroll
            for (int Mt = 0; Mt < 4; ++Mt) {
                f32x4 ee = (Mt == 0) ? e0 : (Mt == 1) ? e1 : (Mt == 2) ? e2 : e3;
                #pragma unroll
                for (int r = 0; r < 4; ++r) {
                    const int row = 16 * Mt + 4 * g + r;
                    *(float*)(slice + SIG_OFF + row * 4) = fmaf(ee[r], 0.125f, w.b2v[0]);
                }
            }
        } else if (o < 33) {
            #pragma unroll
            for (int Mt = 0; Mt < 4; ++Mt) {
                f32x4 ee = (Mt == 0) ? e0 : (Mt == 1) ? e1 : (Mt == 2) ? e2 : e3;
                #pragma unroll
                for (int r = 0; r < 4; ++r) {
                    const float vv = fmaf(ee[r], 0.125f, w.b2v[Nt2]);
                    const float rr = sigmoid_f(vv) * 1.002f - 0.001f;
                    const int row = 16 * Mt + 4 * g + r;
                    *(__half*)(slice + row * 80 + (o - 1) * 2) = __float2half(rr);
                }
            }
        }
    }
}

__global__ __launch_bounds__(THREADS)
void k_fused(const float* __restrict__ planes,
             const float* __restrict__ coords, const float* __restrict__ depths,
             const float* __restrict__ w1, const float* __restrict__ b1,
             const float* __restrict__ w2, const float* __restrict__ b2,
             float* __restrict__ out)
{
    __shared__ __align__(16) char sm[6 * SLICE];
    const int t = threadIdx.x;
    const int wv = t >> 6;
    const int l = t & 63;
    const int g = l >> 4;
    const int ln = l & 15;
    char* const slice = sm + wv * SLICE;

    const int msamp = blockIdx.x * THREADS + t;
    const int nb = (msamp >= M_TOTAL / NB) ? 1 : 0;

    Wreg w;
    load_weights(w, w1, b1, w2, b2, g, ln);

    const float* cp = coords + (size_t)msamp * 3;
    const float c0 = cp[0], c1 = cp[1], c2v = cp[2];
    const float myDep = depths[msamp];

    float xf32[CF];
    #pragma unroll
    for (int c = 0; c < CF; ++c) xf32[c] = 0.f;

    #pragma unroll
    for (int p = 0; p < 3; ++p) {
        const float u = (p == 2) ? c2v : c0;
        const float v = (p == 0) ? c1 : ((p == 1) ? c2v : c0);
        const float xf = fmaf(u, 128.f, 127.5f);
        const float yf = fmaf(v, 128.f, 127.5f);
        const float x0f = floorf(xf), y0f = floorf(yf);
        const float wx = xf - x0f, wy = yf - y0f;
        const int x0 = (int)x0f, y0 = (int)y0f;
        const float vx0 = (x0 >= 0 && x0 < HW) ? 1.f : 0.f;
        const float vx1 = (x0 + 1 >= 0 && x0 + 1 < HW) ? 1.f : 0.f;
        const float vy0 = (y0 >= 0 && y0 < HW) ? 1.f : 0.f;
        const float vy1 = (y0 + 1 >= 0 && y0 + 1 < HW) ? 1.f : 0.f;
        const int xc0 = min(max(x0, 0), HW - 1), xc1 = min(max(x0 + 1, 0), HW - 1);
        const int yc0 = min(max(y0, 0), HW - 1), yc1 = min(max(y0 + 1, 0), HW - 1);
        const float w00 = (1.f - wx) * (1.f - wy) * vx0 * vy0;
        const float w10 = wx * (1.f - wy) * vx1 * vy0;
        const float w01 = (1.f - wx) * wy * vx0 * vy1;
        const float w11 = wx * wy * vx1 * vy1;

        const float* pb = planes + (((size_t)(nb * 3 + p) * CF) << 16);
        const int i00 = yc0 * HW + xc0, i10 = yc0 * HW + xc1;
        const int i01 = yc1 * HW + xc0, i11 = yc1 * HW + xc1;
        #pragma unroll
        for (int c = 0; c < CF; ++c) {
            const float* pc = pb + ((size_t)c << 16);
            float a0 = fmaf(w00, pc[i00], fmaf(w10, pc[i10], 0.f));
            float a1v = fmaf(w01, pc[i01], fmaf(w11, pc[i11], 0.f));
            xf32[c] += a0 + a1v;
        }
    }

    #pragma unroll
    for (int c = 0; c < 4; ++c) {
        union { __half2 h[4]; i32x4 v; } u4;
        #pragma unroll
        for (int j = 0; j < 4; ++j)
            u4.h[j] = __floats2half2_rn(xf32[8 * c + 2 * j], xf32[8 * c + 2 * j + 1]);
        *(i32x4*)(slice + l * 80 + c * 16) = u4.v;
    }

    f16x8 a1[4];
    #pragma unroll
    for (int Mt = 0; Mt < 4; ++Mt)
        a1[Mt] = *(const f16x8*)(slice + (16 * Mt + ln) * 80 + g * 16);

    mlp_slice(slice, a1, w, g, ln);
    *(float*)(slice + DEP_OFF + l * 4) = myDep;

    __syncthreads();

    if (t < 128) {
        const int crl = t >> 5;
        const int c = t & 31;
        const int bs = crl * SAMP;
        auto sigAt = [&](int sb) -> float {
            return *(const float*)(sm + (sb >> 6) * SLICE + SIG_OFF + (sb & 63) * 4);
        };
        auto depAt = [&](int sb) -> float {
            return *(const float*)(sm + (sb >> 6) * SLICE + DEP_OFF + (sb & 63) * 4);
        };
        auto rgbAt = [&](int sb) -> float {
            return __half2float(*(const __half*)(sm + (sb >> 6) * SLICE + (sb & 63) * 80 + c * 2));
        };
        float T = 1.f, a_out = 0.f;
        float sp = sigAt(bs), dp = depAt(bs), rp = rgbAt(bs);
        for (int ss = 1; ss < SAMP; ++ss) {
            const float sc = sigAt(bs + ss);
            const float dc = depAt(bs + ss);
            const float rc = rgbAt(bs + ss);
            const float dens = softplus_f(0.5f * (sp + sc) - 1.f);
            const float alpha = 1.f - __expf(-(dc - dp) * dens);
            a_out = fmaf(alpha * T, 0.5f * (rp + rc), a_out);
            T *= 1.f - alpha + 1e-10f;
            sp = sc; dp = dc; rp = rc;
        }
        out[(size_t)(blockIdx.x * 4 + crl) * CF + c] = fmaf(a_out, 2.f, -1.f);
    }
}

extern "C" void kernel_launch(void* const* d_in, const int* in_sizes, int n_in,
                              void* d_out, int out_size, void* d_ws, size_t ws_size,
                              hipStream_t stream) {
    (void)in_sizes; (void)n_in; (void)out_size;
    const float* planes = (const float*)d_in[0];
    const float* coords = (const float*)d_in[1];
    const float* depths = (const float*)d_in[2];
    const float* w1 = (const float*)d_in[3];
    const float* b1 = (const float*)d_in[4];
    const float* w2 = (const float*)d_in[5];
    const float* b2 = (const float*)d_in[6];
    float* out = (float*)d_out;

    const size_t ptBytes  = (size_t)NB * 3 * PTEX * CF * sizeof(__half);   // 25.56 MB
    const size_t rgbBytes = (size_t)M_TOTAL * CF * sizeof(__half);         // 50.33 MB
    const size_t sigBytes = (size_t)M_TOTAL * sizeof(float);               //  3.15 MB

    dim3 tgrid((PTEX + 255) / 256, NB * 3);   // (261, 6)

    if (ws_size >= ptBytes + rgbBytes + sigBytes) {
        __half2* pt = (__half2*)d_ws;
        __half* rgbW = (__half*)((char*)d_ws + ptBytes);
        float* sigW = (float*)((char*)d_ws + ptBytes + rgbBytes);
        k_transposeB<<<tgrid, 256, 0, stream>>>(planes, pt);
        k_gmlpB<<<M_TOTAL / TG, TG, 0, stream>>>(pt, coords, w1, b1, w2, b2, rgbW, sigW);
        k_comp<<<NB * RAYS / 16, 512, 0, stream>>>(rgbW, sigW, depths, out);
    } else {
        k_fused<<<M_TOTAL / THREADS, THREADS, 0, stream>>>(planes, coords, depths,
                                                           w1, b1, w2, b2, out);
    }
}

// Round 13
// 168.713 us; speedup vs baseline: 1.1530x; 1.0127x over previous
//
#include <hip/hip_runtime.h>
#include <hip/hip_fp16.h>

#define NB 2
#define RAYS 4096
#define SAMP 96
#define CF 32
#define HID 64
#define HW 256
#define PW 258                  // padded plane width (1-texel zero border)
#define PTEX (PW * PW)          // 66564 texels per plane

constexpr int M_TOTAL = NB * RAYS * SAMP;   // 786432 samples

typedef _Float16 f16x8 __attribute__((ext_vector_type(8)));
typedef float f32x4 __attribute__((ext_vector_type(4)));
typedef int i32x4 __attribute__((ext_vector_type(4)));

__device__ __forceinline__ float softplus_f(float z) {
    return fmaxf(z, 0.f) + __logf(1.f + __expf(-fabsf(z)));
}
__device__ __forceinline__ float sigmoid_f(float z) {
    return __fdividef(1.f, 1.f + __expf(-z));
}

// planes (N,3,C,256,256) f32 -> pt (N*3, 258, 258, C) f16, zero border.
__global__ __launch_bounds__(256)
void k_transposeB(const float* __restrict__ src, __half2* __restrict__ dst) {
    const int xy = blockIdx.x * 256 + threadIdx.x;
    const int pn = blockIdx.y;                    // n*3+p in [0,6)
    if (xy >= PTEX) return;
    const int y = xy / PW;
    const int x = xy - y * PW;
    __half2 v[16];
    if (x >= 1 && x <= HW && y >= 1 && y <= HW) {
        const float* s = src + (((size_t)pn * CF) << 16) + (y - 1) * HW + (x - 1);
        #pragma unroll
        for (int c2 = 0; c2 < 16; ++c2) {
            const float a = s[((size_t)(2 * c2)) << 16];
            const float b = s[((size_t)(2 * c2 + 1)) << 16];
            v[c2] = __floats2half2_rn(a, b);
        }
    } else {
        #pragma unroll
        for (int c2 = 0; c2 < 16; ++c2) v[c2] = __float2half2_rn(0.f);
    }
    __half2* d = dst + ((size_t)pn * PTEX + xy) * 16;
    #pragma unroll
    for (int q = 0; q < 4; ++q)
        ((i32x4*)d)[q] = ((const i32x4*)v)[q];
}

// ---- shared device pieces (fallback path) ----
struct Wreg {
    f16x8 b1f[4];  float b1v[4];
    f16x8 b2f[3][2]; float b2v[3];
};

__device__ __forceinline__ void load_weights(Wreg& w,
        const float* __restrict__ w1, const float* __restrict__ b1,
        const float* __restrict__ w2, const float* __restrict__ b2,
        int g, int ln) {
    #pragma unroll
    for (int Nt = 0; Nt < 4; ++Nt) {
        const int hn = 16 * Nt + ln;
        const float4* p0 = (const float4*)(w1 + hn * CF + g * 8);
        float4 u = p0[0], v = p0[1];
        w.b1f[Nt][0] = (_Float16)u.x; w.b1f[Nt][1] = (_Float16)u.y;
        w.b1f[Nt][2] = (_Float16)u.z; w.b1f[Nt][3] = (_Float16)u.w;
        w.b1f[Nt][4] = (_Float16)v.x; w.b1f[Nt][5] = (_Float16)v.y;
        w.b1f[Nt][6] = (_Float16)v.z; w.b1f[Nt][7] = (_Float16)v.w;
        w.b1v[Nt] = b1[hn];
    }
    #pragma unroll
    for (int Nt2 = 0; Nt2 < 3; ++Nt2) {
        const int o = 16 * Nt2 + ln;
        if (o < 33) {
            #pragma unroll
            for (int kh = 0; kh < 2; ++kh) {
                const float4* p0 = (const float4*)(w2 + o * HID + kh * 32 + g * 8);
                float4 u = p0[0], v = p0[1];
                w.b2f[Nt2][kh][0] = (_Float16)u.x; w.b2f[Nt2][kh][1] = (_Float16)u.y;
                w.b2f[Nt2][kh][2] = (_Float16)u.z; w.b2f[Nt2][kh][3] = (_Float16)u.w;
                w.b2f[Nt2][kh][4] = (_Float16)v.x; w.b2f[Nt2][kh][5] = (_Float16)v.y;
                w.b2f[Nt2][kh][6] = (_Float16)v.z; w.b2f[Nt2][kh][7] = (_Float16)v.w;
            }
            w.b2v[Nt2] = b2[o];
        } else {
            #pragma unroll
            for (int kh = 0; kh < 2; ++kh)
                #pragma unroll
                for (int i = 0; i < 8; ++i) w.b2f[Nt2][kh][i] = (_Float16)0.f;
            w.b2v[Nt2] = 0.f;
        }
    }
}

// 4-lane cooperative gather (fallback path; main kernel inlines p-outer form)
__device__ __forceinline__ f16x8 gather4(const __half* __restrict__ ptb,
                                         float c0, float c1, float c2v, int g) {
    __half2 acc4[4];
    #pragma unroll
    for (int j = 0; j < 4; ++j) acc4[j] = __float2half2_rn(0.f);

    #pragma unroll
    for (int p = 0; p < 3; ++p) {
        const float u = (p == 2) ? c2v : c0;
        const float v = (p == 0) ? c1 : ((p == 1) ? c2v : c0);
        const float xf = fmaf(u, 128.f, 127.5f);
        const float yf = fmaf(v, 128.f, 127.5f);
        const float x0f = floorf(xf), y0f = floorf(yf);
        const float wx = xf - x0f, wy = yf - y0f;
        const int x0 = (int)x0f, y0 = (int)y0f;
        const int base = (y0 + 1) * PW + (x0 + 1);
        const __half* tp = ptb + (size_t)p * (PTEX * CF) + (size_t)base * CF + g * 8;
        const float w00 = (1.f - wx) * (1.f - wy);
        const float w10 = wx * (1.f - wy);
        const float w01 = (1.f - wx) * wy;
        const float w11 = wx * wy;
        auto tapf = [&](const __half* q, float w) {
            union { float4 f; __half2 h[4]; } u4;
            u4.f = *(const float4*)q;
            const __half2 wh = __float2half2_rn(w);
            acc4[0] = __hfma2(wh, u4.h[0], acc4[0]);
            acc4[1] = __hfma2(wh, u4.h[1], acc4[1]);
            acc4[2] = __hfma2(wh, u4.h[2], acc4[2]);
            acc4[3] = __hfma2(wh, u4.h[3], acc4[3]);
        };
        tapf(tp, w00);
        tapf(tp + CF, w10);
        tapf(tp + PW * CF, w01);
        tapf(tp + PW * CF + CF, w11);
    }
    union { __half2 h[4]; f16x8 f; } uf;
    #pragma unroll
    for (int j = 0; j < 4; ++j) uf.h[j] = acc4[j];
    return uf.f;
}

constexpr float IS32_3 = 0.058925565098879624f;   // (1/sqrt(32)) / 3

// ============== split path: gather+MLP ==============
// r13: PHASE-COHERENT gather — loop order p OUTER, Mt inner. All waves start
// in phase and execute the same unrolled stream, so during phase p the XCD's
// L2 working set is ONE 4.26MB plane slab (~= 4MB L2) instead of 12.8MB.
// Everything else = r12 (JIT weights + sched_barrier, XCD batch partition,
// 18.4KB LDS, 4-lane coalesced taps, padded border table).
constexpr int TG = 128;
constexpr int SLICE_A = 9216;   // per-wave LDS slice bytes
constexpr int SIGO = 5120;      // sigma region (float[64])

__global__ __launch_bounds__(TG)
void k_gmlpB(const __half2* __restrict__ pt, const float* __restrict__ coords,
             const float* __restrict__ w1, const float* __restrict__ b1,
             const float* __restrict__ w2, const float* __restrict__ b2,
             __half* __restrict__ rgbW, float* __restrict__ sigW)
{
    __shared__ __align__(16) char sm[2 * SLICE_A];   // 18.4 KB
    const int t = threadIdx.x;
    const int wv = t >> 6;
    const int l = t & 63;
    const int g = l >> 4;
    const int ln = l & 15;
    char* const slice = sm + wv * SLICE_A;

    // ---- XCD-partitioned block->sample mapping (r11) ----
    const int bid = blockIdx.x;                 // 6144 = 768 * 8
    const int xcd = bid & 7;
    const int nb = xcd >> 2;                    // XCDs 0-3: batch 0; 4-7: batch 1
    const int rank = (bid >> 3) * 4 + (xcd & 3);   // 0..3071 within batch
    const int waveBaseS = nb * (M_TOTAL / NB) + rank * TG + wv * 64;
    const __half* ptb = (const __half*)pt + (size_t)nb * 3 * (PTEX * CF);

    // ---- coords prefetch (4 independent triples) ----
    float cx[4], cy[4], cz[4];
    #pragma unroll
    for (int Mt = 0; Mt < 4; ++Mt) {
        const float* cp = coords + (size_t)(waveBaseS + 16 * Mt + ln) * 3;
        cx[Mt] = cp[0]; cy[Mt] = cp[1]; cz[Mt] = cp[2];
    }

    // ---- gather, p-OUTER: one plane slab at a time across all waves ----
    __half2 acc[4][4];
    #pragma unroll
    for (int Mt = 0; Mt < 4; ++Mt)
        #pragma unroll
        for (int j = 0; j < 4; ++j) acc[Mt][j] = __float2half2_rn(0.f);

    #pragma unroll
    for (int p = 0; p < 3; ++p) {
        const __half* pp = ptb + (size_t)p * (PTEX * CF) + g * 8;
        #pragma unroll
        for (int Mt = 0; Mt < 4; ++Mt) {
            const float u = (p == 2) ? cz[Mt] : cx[Mt];
            const float v = (p == 0) ? cy[Mt] : ((p == 1) ? cz[Mt] : cx[Mt]);
            const float xf = fmaf(u, 128.f, 127.5f);
            const float yf = fmaf(v, 128.f, 127.5f);
            const float x0f = floorf(xf), y0f = floorf(yf);
            const float wx = xf - x0f, wy = yf - y0f;
            const int x0 = (int)x0f, y0 = (int)y0f;        // in [-1, 255]
            const int base = (y0 + 1) * PW + (x0 + 1);      // border handles OOB
            const __half* tp = pp + (size_t)base * CF;
            const float w00 = (1.f - wx) * (1.f - wy);
            const float w10 = wx * (1.f - wy);
            const float w01 = (1.f - wx) * wy;
            const float w11 = wx * wy;
            auto tapf = [&](const __half* q, float wq) {
                union { float4 f; __half2 h[4]; } u4;
                u4.f = *(const float4*)q;                   // lanes g=0..3 share one 64B line
                const __half2 wh = __float2half2_rn(wq);
                acc[Mt][0] = __hfma2(wh, u4.h[0], acc[Mt][0]);
                acc[Mt][1] = __hfma2(wh, u4.h[1], acc[Mt][1]);
                acc[Mt][2] = __hfma2(wh, u4.h[2], acc[Mt][2]);
                acc[Mt][3] = __hfma2(wh, u4.h[3], acc[Mt][3]);
            };
            tapf(tp, w00);
            tapf(tp + CF, w10);
            tapf(tp + PW * CF, w01);
            tapf(tp + PW * CF + CF, w11);
        }
    }

    f16x8 a1[4];
    #pragma unroll
    for (int Mt = 0; Mt < 4; ++Mt) {
        union { __half2 h[4]; f16x8 f; } uf;
        #pragma unroll
        for (int j = 0; j < 4; ++j) uf.h[j] = acc[Mt][j];
        a1[Mt] = uf.f;
    }

    // fence: keep weight loads OUT of the gather region (live-range control)
    __builtin_amdgcn_sched_barrier(0);

    // ---- layer 1: load w1 fragments just-in-time, then MFMA -> h in LDS ----
    f16x8 b1f[4];
    float b1v[4];
    #pragma unroll
    for (int Nt = 0; Nt < 4; ++Nt) {
        const int hn = 16 * Nt + ln;
        const float4* p0 = (const float4*)(w1 + hn * CF + g * 8);
        float4 u = p0[0], v = p0[1];
        b1f[Nt][0] = (_Float16)u.x; b1f[Nt][1] = (_Float16)u.y;
        b1f[Nt][2] = (_Float16)u.z; b1f[Nt][3] = (_Float16)u.w;
        b1f[Nt][4] = (_Float16)v.x; b1f[Nt][5] = (_Float16)v.y;
        b1f[Nt][6] = (_Float16)v.z; b1f[Nt][7] = (_Float16)v.w;
        b1v[Nt] = b1[hn];
    }

    #pragma unroll
    for (int Nt = 0; Nt < 4; ++Nt) {
        f32x4 d0 = {0.f, 0.f, 0.f, 0.f};
        f32x4 d1 = {0.f, 0.f, 0.f, 0.f};
        f32x4 d2 = {0.f, 0.f, 0.f, 0.f};
        f32x4 d3 = {0.f, 0.f, 0.f, 0.f};
        d0 = __builtin_amdgcn_mfma_f32_16x16x32_f16(a1[0], b1f[Nt], d0, 0, 0, 0);
        d1 = __builtin_amdgcn_mfma_f32_16x16x32_f16(a1[1], b1f[Nt], d1, 0, 0, 0);
        d2 = __builtin_amdgcn_mfma_f32_16x16x32_f16(a1[2], b1f[Nt], d2, 0, 0, 0);
        d3 = __builtin_amdgcn_mfma_f32_16x16x32_f16(a1[3], b1f[Nt], d3, 0, 0, 0);
        const int hcol = 16 * Nt + ln;
        #pragma unroll
        for (int Mt = 0; Mt < 4; ++Mt) {
            f32x4 dd = (Mt == 0) ? d0 : (Mt == 1) ? d1 : (Mt == 2) ? d2 : d3;
            #pragma unroll
            for (int r = 0; r < 4; ++r) {
                const float hv = softplus_f(fmaf(dd[r], IS32_3, b1v[Nt]));
                const int row = 16 * Mt + 4 * g + r;
                *(__half*)(slice + row * 144 + hcol * 2) = __float2half(hv);
            }
        }
    }

    // ---- layer-2 A-fragments (h transposed via LDS) ----
    f16x8 a2[4][2];
    #pragma unroll
    for (int Mt = 0; Mt < 4; ++Mt)
        #pragma unroll
        for (int kh = 0; kh < 2; ++kh)
            a2[Mt][kh] = *(const f16x8*)(slice + (16 * Mt + ln) * 144 + (kh * 4 + g) * 16);

    // ---- layer 2: w2 fragments loaded just-in-time inside the loop ----
    #pragma unroll
    for (int Nt2 = 0; Nt2 < 3; ++Nt2) {
        const int o = 16 * Nt2 + ln;
        f16x8 f0, f1;
        float bv;
        if (o < 33) {
            const float4* p0 = (const float4*)(w2 + o * HID + g * 8);
            float4 u = p0[0], v = p0[1];
            f0[0] = (_Float16)u.x; f0[1] = (_Float16)u.y;
            f0[2] = (_Float16)u.z; f0[3] = (_Float16)u.w;
            f0[4] = (_Float16)v.x; f0[5] = (_Float16)v.y;
            f0[6] = (_Float16)v.z; f0[7] = (_Float16)v.w;
            const float4* p1 = (const float4*)(w2 + o * HID + 32 + g * 8);
            float4 u1 = p1[0], v1 = p1[1];
            f1[0] = (_Float16)u1.x; f1[1] = (_Float16)u1.y;
            f1[2] = (_Float16)u1.z; f1[3] = (_Float16)u1.w;
            f1[4] = (_Float16)v1.x; f1[5] = (_Float16)v1.y;
            f1[6] = (_Float16)v1.z; f1[7] = (_Float16)v1.w;
            bv = b2[o];
        } else {
            #pragma unroll
            for (int i = 0; i < 8; ++i) { f0[i] = (_Float16)0.f; f1[i] = (_Float16)0.f; }
            bv = 0.f;
        }
        f32x4 e0 = {0.f, 0.f, 0.f, 0.f};
        f32x4 e1 = {0.f, 0.f, 0.f, 0.f};
        f32x4 e2 = {0.f, 0.f, 0.f, 0.f};
        f32x4 e3 = {0.f, 0.f, 0.f, 0.f};
        e0 = __builtin_amdgcn_mfma_f32_16x16x32_f16(a2[0][0], f0, e0, 0, 0, 0);
        e1 = __builtin_amdgcn_mfma_f32_16x16x32_f16(a2[1][0], f0, e1, 0, 0, 0);
        e2 = __builtin_amdgcn_mfma_f32_16x16x32_f16(a2[2][0], f0, e2, 0, 0, 0);
        e3 = __builtin_amdgcn_mfma_f32_16x16x32_f16(a2[3][0], f0, e3, 0, 0, 0);
        e0 = __builtin_amdgcn_mfma_f32_16x16x32_f16(a2[0][1], f1, e0, 0, 0, 0);
        e1 = __builtin_amdgcn_mfma_f32_16x16x32_f16(a2[1][1], f1, e1, 0, 0, 0);
        e2 = __builtin_amdgcn_mfma_f32_16x16x32_f16(a2[2][1], f1, e2, 0, 0, 0);
        e3 = __builtin_amdgcn_mfma_f32_16x16x32_f16(a2[3][1], f1, e3, 0, 0, 0);
        if (o == 0) {
            #pragma unroll
            for (int Mt = 0; Mt < 4; ++Mt) {
                f32x4 ee = (Mt == 0) ? e0 : (Mt == 1) ? e1 : (Mt == 2) ? e2 : e3;
                #pragma unroll
                for (int r = 0; r < 4; ++r) {
                    const int row = 16 * Mt + 4 * g + r;
                    *(float*)(slice + SIGO + row * 4) = fmaf(ee[r], 0.125f, bv);
                }
            }
        } else if (o < 33) {
            #pragma unroll
            for (int Mt = 0; Mt < 4; ++Mt) {
                f32x4 ee = (Mt == 0) ? e0 : (Mt == 1) ? e1 : (Mt == 2) ? e2 : e3;
                #pragma unroll
                for (int r = 0; r < 4; ++r) {
                    const float vv = fmaf(ee[r], 0.125f, bv);
                    const float rr = sigmoid_f(vv) * 1.002f - 0.001f;
                    const int row = 16 * Mt + 4 * g + r;
                    *(__half*)(slice + row * 80 + (o - 1) * 2) = __float2half(rr);
                }
            }
        }
    }

    // ---- coalesced nontemporal stores of rgb + sigma ----
    const int q0 = l & 3, r0 = l >> 2;
    #pragma unroll
    for (int q = 0; q < 4; ++q) {
        const int row = 16 * q + r0;
        i32x4 v = *(const i32x4*)(slice + row * 80 + q0 * 16);
        __builtin_nontemporal_store(v,
            (i32x4*)((char*)rgbW + (size_t)(waveBaseS + row) * 64 + q0 * 16));
    }
    const float sv = *(const float*)(slice + SIGO + l * 4);
    __builtin_nontemporal_store(sv, sigW + waveBaseS + l);
}

// ============== split path: composite ==============
__global__ __launch_bounds__(512)
void k_comp(const __half* __restrict__ rgbW, const float* __restrict__ sigW,
            const float* __restrict__ depths, float* __restrict__ out)
{
    __shared__ float sgS[16 * SAMP];
    __shared__ float dpS[16 * SAMP];
    const int t = threadIdx.x;
    const int rayBase = blockIdx.x * 16;
    for (int i = t; i < 16 * SAMP; i += 512) {
        sgS[i] = sigW[(size_t)rayBase * SAMP + i];
        dpS[i] = depths[(size_t)rayBase * SAMP + i];
    }
    __syncthreads();

    const int rs = t >> 5;
    const int c = t & 31;
    const size_t mb = (size_t)(rayBase + rs) * SAMP;
    const ushort* rgbU = (const ushort*)rgbW;

    auto ldr = [&](size_t idx) -> float {
        ushort u = __builtin_nontemporal_load(rgbU + idx);
        __half h = *(__half*)&u;
        return __half2float(h);
    };

    float T = 1.f, a_out = 0.f;
    float sp = sgS[rs * SAMP], dp = dpS[rs * SAMP];
    float rp = ldr(mb * 32 + c);
    float rnx = ldr((mb + 1) * 32 + c);
    #pragma unroll 2
    for (int ss = 1; ss < SAMP; ++ss) {
        const float rc = rnx;
        const int nxt = (ss + 1 < SAMP) ? (ss + 1) : (SAMP - 1);
        rnx = ldr((mb + nxt) * 32 + c);
        const float sc = sgS[rs * SAMP + ss];
        const float dc = dpS[rs * SAMP + ss];
        const float dens = softplus_f(0.5f * (sp + sc) - 1.f);
        const float alpha = 1.f - __expf(-(dc - dp) * dens);
        a_out = fmaf(alpha * T, 0.5f * (rp + rc), a_out);
        T *= 1.f - alpha + 1e-10f;
        sp = sc; dp = dc; rp = rc;
    }
    out[(size_t)(rayBase + rs) * CF + c] = fmaf(a_out, 2.f, -1.f);
}

// ============== fallback: direct from planes (no workspace) ==============
constexpr int THREADS = 384;
constexpr int SLICE = 9216;
constexpr int SIG_OFF = 5120;
constexpr int DEP_OFF = 5376;

__device__ __forceinline__ void mlp_slice(char* slice, const f16x8 a1[4],
                                          const Wreg& w, int g, int ln) {
    #pragma unroll
    for (int Nt = 0; Nt < 4; ++Nt) {
        f32x4 d0 = {0.f, 0.f, 0.f, 0.f};
        f32x4 d1 = {0.f, 0.f, 0.f, 0.f};
        f32x4 d2 = {0.f, 0.f, 0.f, 0.f};
        f32x4 d3 = {0.f, 0.f, 0.f, 0.f};
        d0 = __builtin_amdgcn_mfma_f32_16x16x32_f16(a1[0], w.b1f[Nt], d0, 0, 0, 0);
        d1 = __builtin_amdgcn_mfma_f32_16x16x32_f16(a1[1], w.b1f[Nt], d1, 0, 0, 0);
        d2 = __builtin_amdgcn_mfma_f32_16x16x32_f16(a1[2], w.b1f[Nt], d2, 0, 0, 0);
        d3 = __builtin_amdgcn_mfma_f32_16x16x32_f16(a1[3], w.b1f[Nt], d3, 0, 0, 0);
        const int hcol = 16 * Nt + ln;
        #pragma unroll
        for (int Mt = 0; Mt < 4; ++Mt) {
            f32x4 dd = (Mt == 0) ? d0 : (Mt == 1) ? d1 : (Mt == 2) ? d2 : d3;
            #pragma unroll
            for (int r = 0; r < 4; ++r) {
                const float hv = softplus_f(fmaf(dd[r], IS32_3, w.b1v[Nt]));
                const int row = 16 * Mt + 4 * g + r;
                *(__half*)(slice + row * 144 + hcol * 2) = __float2half(hv);
            }
        }
    }

    f16x8 a2[4][2];
    #pragma unroll
    for (int Mt = 0; Mt < 4; ++Mt)
        #pragma unroll
        for (int kh = 0; kh < 2; ++kh)
            a2[Mt][kh] = *(const f16x8*)(slice + (16 * Mt + ln) * 144 + (kh * 4 + g) * 16);

    #pragma unroll
    for (int Nt2 = 0; Nt2 < 3; ++Nt2) {
        f32x4 e0 = {0.f, 0.f, 0.f, 0.f};
        f32x4 e1 = {0.f, 0.f, 0.f, 0.f};
        f32x4 e2 = {0.f, 0.f, 0.f, 0.f};
        f32x4 e3 = {0.f, 0.f, 0.f, 0.f};
        #pragma unroll
        for (int kh = 0; kh < 2; ++kh) {
            e0 = __builtin_amdgcn_mfma_f32_16x16x32_f16(a2[0][kh], w.b2f[Nt2][kh], e0, 0, 0, 0);
            e1 = __builtin_amdgcn_mfma_f32_16x16x32_f16(a2[1][kh], w.b2f[Nt2][kh], e1, 0, 0, 0);
            e2 = __builtin_amdgcn_mfma_f32_16x16x32_f16(a2[2][kh], w.b2f[Nt2][kh], e2, 0, 0, 0);
            e3 = __builtin_amdgcn_mfma_f32_16x16x32_f16(a2[3][kh], w.b2f[Nt2][kh], e3, 0, 0, 0);
        }
        const int o = 16 * Nt2 + ln;
        if (o == 0) {
            #pragma unroll
            for (int Mt = 0; Mt < 4; ++Mt) {
                f32x4 ee = (Mt == 0) ? e0 : (Mt == 1) ? e1 : (Mt == 2) ? e2 : e3;
                #pragma unroll
                for (int r = 0; r < 4; ++r) {
                    const int row = 16 * Mt + 4 * g + r;
                    *(float*)(slice + SIG_OFF + row * 4) = fmaf(ee[r], 0.125f, w.b2v[0]);
                }
            }
        } else if (o < 33) {
            #pragma unroll
            for (int Mt = 0; Mt < 4; ++Mt) {
                f32x4 ee = (Mt == 0) ? e0 : (Mt == 1) ? e1 : (Mt == 2) ? e2 : e3;
                #pragma unroll
                for (int r = 0; r < 4; ++r) {
                    const float vv = fmaf(ee[r], 0.125f, w.b2v[Nt2]);
                    const float rr = sigmoid_f(vv) * 1.002f - 0.001f;
                    const int row = 16 * Mt + 4 * g + r;
                    *(__half*)(slice + row * 80 + (o - 1) * 2) = __float2half(rr);
                }
            }
        }
    }
}

__global__ __launch_bounds__(THREADS)
void k_fused(const float* __restrict__ planes,
             const float* __restrict__ coords, const float* __restrict__ depths,
             const float* __restrict__ w1, const float* __restrict__ b1,
             const float* __restrict__ w2, const float* __restrict__ b2,
             float* __restrict__ out)
{
    __shared__ __align__(16) char sm[6 * SLICE];
    const int t = threadIdx.x;
    const int wv = t >> 6;
    const int l = t & 63;
    const int g = l >> 4;
    const int ln = l & 15;
    char* const slice = sm + wv * SLICE;

    const int msamp = blockIdx.x * THREADS + t;
    const int nb = (msamp >= M_TOTAL / NB) ? 1 : 0;

    Wreg w;
    load_weights(w, w1, b1, w2, b2, g, ln);

    const float* cp = coords + (size_t)msamp * 3;
    const float c0 = cp[0], c1 = cp[1], c2v = cp[2];
    const float myDep = depths[msamp];

    float xf32[CF];
    #pragma unroll
    for (int c = 0; c < CF; ++c) xf32[c] = 0.f;

    #pragma unroll
    for (int p = 0; p < 3; ++p) {
        const float u = (p == 2) ? c2v : c0;
        const float v = (p == 0) ? c1 : ((p == 1) ? c2v : c0);
        const float xf = fmaf(u, 128.f, 127.5f);
        const float yf = fmaf(v, 128.f, 127.5f);
        const float x0f = floorf(xf), y0f = floorf(yf);
        const float wx = xf - x0f, wy = yf - y0f;
        const int x0 = (int)x0f, y0 = (int)y0f;
        const float vx0 = (x0 >= 0 && x0 < HW) ? 1.f : 0.f;
        const float vx1 = (x0 + 1 >= 0 && x0 + 1 < HW) ? 1.f : 0.f;
        const float vy0 = (y0 >= 0 && y0 < HW) ? 1.f : 0.f;
        const float vy1 = (y0 + 1 >= 0 && y0 + 1 < HW) ? 1.f : 0.f;
        const int xc0 = min(max(x0, 0), HW - 1), xc1 = min(max(x0 + 1, 0), HW - 1);
        const int yc0 = min(max(y0, 0), HW - 1), yc1 = min(max(y0 + 1, 0), HW - 1);
        const float w00 = (1.f - wx) * (1.f - wy) * vx0 * vy0;
        const float w10 = wx * (1.f - wy) * vx1 * vy0;
        const float w01 = (1.f - wx) * wy * vx0 * vy1;
        const float w11 = wx * wy * vx1 * vy1;

        const float* pb = planes + (((size_t)(nb * 3 + p) * CF) << 16);
        const int i00 = yc0 * HW + xc0, i10 = yc0 * HW + xc1;
        const int i01 = yc1 * HW + xc0, i11 = yc1 * HW + xc1;
        #pragma unroll
        for (int c = 0; c < CF; ++c) {
            const float* pc = pb + ((size_t)c << 16);
            float a0 = fmaf(w00, pc[i00], fmaf(w10, pc[i10], 0.f));
            float a1v = fmaf(w01, pc[i01], fmaf(w11, pc[i11], 0.f));
            xf32[c] += a0 + a1v;
        }
    }

    #pragma unroll
    for (int c = 0; c < 4; ++c) {
        union { __half2 h[4]; i32x4 v; } u4;
        #pragma unroll
        for (int j = 0; j < 4; ++j)
            u4.h[j] = __floats2half2_rn(xf32[8 * c + 2 * j], xf32[8 * c + 2 * j + 1]);
        *(i32x4*)(slice + l * 80 + c * 16) = u4.v;
    }

    f16x8 a1[4];
    #pragma unroll
    for (int Mt = 0; Mt < 4; ++Mt)
        a1[Mt] = *(const f16x8*)(slice + (16 * Mt + ln) * 80 + g * 16);

    mlp_slice(slice, a1, w, g, ln);
    *(float*)(slice + DEP_OFF + l * 4) = myDep;

    __syncthreads();

    if (t < 128) {
        const int crl = t >> 5;
        const int c = t & 31;
        const int bs = crl * SAMP;
        auto sigAt = [&](int sb) -> float {
            return *(const float*)(sm + (sb >> 6) * SLICE + SIG_OFF + (sb & 63) * 4);
        };
        auto depAt = [&](int sb) -> float {
            return *(const float*)(sm + (sb >> 6) * SLICE + DEP_OFF + (sb & 63) * 4);
        };
        auto rgbAt = [&](int sb) -> float {
            return __half2float(*(const __half*)(sm + (sb >> 6) * SLICE + (sb & 63) * 80 + c * 2));
        };
        float T = 1.f, a_out = 0.f;
        float sp = sigAt(bs), dp = depAt(bs), rp = rgbAt(bs);
        for (int ss = 1; ss < SAMP; ++ss) {
            const float sc = sigAt(bs + ss);
            const float dc = depAt(bs + ss);
            const float rc = rgbAt(bs + ss);
            const float dens = softplus_f(0.5f * (sp + sc) - 1.f);
            const float alpha = 1.f - __expf(-(dc - dp) * dens);
            a_out = fmaf(alpha * T, 0.5f * (rp + rc), a_out);
            T *= 1.f - alpha + 1e-10f;
            sp = sc; dp = dc; rp = rc;
        }
        out[(size_t)(blockIdx.x * 4 + crl) * CF + c] = fmaf(a_out, 2.f, -1.f);
    }
}

extern "C" void kernel_launch(void* const* d_in, const int* in_sizes, int n_in,
                              void* d_out, int out_size, void* d_ws, size_t ws_size,
                              hipStream_t stream) {
    (void)in_sizes; (void)n_in; (void)out_size;
    const float* planes = (const float*)d_in[0];
    const float* coords = (const float*)d_in[1];
    const float* depths = (const float*)d_in[2];
    const float* w1 = (const float*)d_in[3];
    const float* b1 = (const float*)d_in[4];
    const float* w2 = (const float*)d_in[5];
    const float* b2 = (const float*)d_in[6];
    float* out = (float*)d_out;

    const size_t ptBytes  = (size_t)NB * 3 * PTEX * CF * sizeof(__half);   // 25.56 MB
    const size_t rgbBytes = (size_t)M_TOTAL * CF * sizeof(__half);         // 50.33 MB
    const size_t sigBytes = (size_t)M_TOTAL * sizeof(float);               //  3.15 MB

    dim3 tgrid((PTEX + 255) / 256, NB * 3);   // (261, 6)

    if (ws_size >= ptBytes + rgbBytes + sigBytes) {
        __half2* pt = (__half2*)d_ws;
        __half* rgbW = (__half*)((char*)d_ws + ptBytes);
        float* sigW = (float*)((char*)d_ws + ptBytes + rgbBytes);
        k_transposeB<<<tgrid, 256, 0, stream>>>(planes, pt);
        k_gmlpB<<<M_TOTAL / TG, TG, 0, stream>>>(pt, coords, w1, b1, w2, b2, rgbW, sigW);
        k_comp<<<NB * RAYS / 16, 512, 0, stream>>>(rgbW, sigW, depths, out);
    } else {
        k_fused<<<M_TOTAL / THREADS, THREADS, 0, stream>>>(planes, coords, depths,
                                                           w1, b1, w2, b2, out);
    }
}

// Round 14
// 147.418 us; speedup vs baseline: 1.3196x; 1.1445x over previous
//
#include <hip/hip_runtime.h>
#include <hip/hip_fp16.h>

#define NB 2
#define RAYS 4096
#define SAMP 96
#define CF 32
#define HID 64
#define HW 256
#define PW 258                  // padded plane width (1-texel zero border)
#define PTEX (PW * PW)          // 66564 texels per plane

constexpr int M_TOTAL = NB * RAYS * SAMP;   // 786432 samples

typedef _Float16 f16x8 __attribute__((ext_vector_type(8)));
typedef float f32x4 __attribute__((ext_vector_type(4)));
typedef int i32x4 __attribute__((ext_vector_type(4)));

__device__ __forceinline__ float softplus_f(float z) {
    return fmaxf(z, 0.f) + __logf(1.f + __expf(-fabsf(z)));
}
__device__ __forceinline__ float sigmoid_f(float z) {
    return __fdividef(1.f, 1.f + __expf(-z));
}

// planes (N,3,C,256,256) f32 -> pt (N*3, 258, 258, C) f16, zero border.
__global__ __launch_bounds__(256)
void k_transposeB(const float* __restrict__ src, __half2* __restrict__ dst) {
    const int xy = blockIdx.x * 256 + threadIdx.x;
    const int pn = blockIdx.y;                    // n*3+p in [0,6)
    if (xy >= PTEX) return;
    const int y = xy / PW;
    const int x = xy - y * PW;
    __half2 v[16];
    if (x >= 1 && x <= HW && y >= 1 && y <= HW) {
        const float* s = src + (((size_t)pn * CF) << 16) + (y - 1) * HW + (x - 1);
        #pragma unroll
        for (int c2 = 0; c2 < 16; ++c2) {
            const float a = s[((size_t)(2 * c2)) << 16];
            const float b = s[((size_t)(2 * c2 + 1)) << 16];
            v[c2] = __floats2half2_rn(a, b);
        }
    } else {
        #pragma unroll
        for (int c2 = 0; c2 < 16; ++c2) v[c2] = __float2half2_rn(0.f);
    }
    __half2* d = dst + ((size_t)pn * PTEX + xy) * 16;
    #pragma unroll
    for (int q = 0; q < 4; ++q)
        ((i32x4*)d)[q] = ((const i32x4*)v)[q];
}

// ---- shared device pieces (fallback path) ----
struct Wreg {
    f16x8 b1f[4];  float b1v[4];
    f16x8 b2f[3][2]; float b2v[3];
};

__device__ __forceinline__ void load_weights(Wreg& w,
        const float* __restrict__ w1, const float* __restrict__ b1,
        const float* __restrict__ w2, const float* __restrict__ b2,
        int g, int ln) {
    #pragma unroll
    for (int Nt = 0; Nt < 4; ++Nt) {
        const int hn = 16 * Nt + ln;
        const float4* p0 = (const float4*)(w1 + hn * CF + g * 8);
        float4 u = p0[0], v = p0[1];
        w.b1f[Nt][0] = (_Float16)u.x; w.b1f[Nt][1] = (_Float16)u.y;
        w.b1f[Nt][2] = (_Float16)u.z; w.b1f[Nt][3] = (_Float16)u.w;
        w.b1f[Nt][4] = (_Float16)v.x; w.b1f[Nt][5] = (_Float16)v.y;
        w.b1f[Nt][6] = (_Float16)v.z; w.b1f[Nt][7] = (_Float16)v.w;
        w.b1v[Nt] = b1[hn];
    }
    #pragma unroll
    for (int Nt2 = 0; Nt2 < 3; ++Nt2) {
        const int o = 16 * Nt2 + ln;
        if (o < 33) {
            #pragma unroll
            for (int kh = 0; kh < 2; ++kh) {
                const float4* p0 = (const float4*)(w2 + o * HID + kh * 32 + g * 8);
                float4 u = p0[0], v = p0[1];
                w.b2f[Nt2][kh][0] = (_Float16)u.x; w.b2f[Nt2][kh][1] = (_Float16)u.y;
                w.b2f[Nt2][kh][2] = (_Float16)u.z; w.b2f[Nt2][kh][3] = (_Float16)u.w;
                w.b2f[Nt2][kh][4] = (_Float16)v.x; w.b2f[Nt2][kh][5] = (_Float16)v.y;
                w.b2f[Nt2][kh][6] = (_Float16)v.z; w.b2f[Nt2][kh][7] = (_Float16)v.w;
            }
            w.b2v[Nt2] = b2[o];
        } else {
            #pragma unroll
            for (int kh = 0; kh < 2; ++kh)
                #pragma unroll
                for (int i = 0; i < 8; ++i) w.b2f[Nt2][kh][i] = (_Float16)0.f;
            w.b2v[Nt2] = 0.f;
        }
    }
}

// 4-lane cooperative gather (fallback path; main kernel inlines p-outer form)
__device__ __forceinline__ f16x8 gather4(const __half* __restrict__ ptb,
                                         float c0, float c1, float c2v, int g) {
    __half2 acc4[4];
    #pragma unroll
    for (int j = 0; j < 4; ++j) acc4[j] = __float2half2_rn(0.f);

    #pragma unroll
    for (int p = 0; p < 3; ++p) {
        const float u = (p == 2) ? c2v : c0;
        const float v = (p == 0) ? c1 : ((p == 1) ? c2v : c0);
        const float xf = fmaf(u, 128.f, 127.5f);
        const float yf = fmaf(v, 128.f, 127.5f);
        const float x0f = floorf(xf), y0f = floorf(yf);
        const float wx = xf - x0f, wy = yf - y0f;
        const int x0 = (int)x0f, y0 = (int)y0f;
        const int base = (y0 + 1) * PW + (x0 + 1);
        const __half* tp = ptb + (size_t)p * (PTEX * CF) + (size_t)base * CF + g * 8;
        const float w00 = (1.f - wx) * (1.f - wy);
        const float w10 = wx * (1.f - wy);
        const float w01 = (1.f - wx) * wy;
        const float w11 = wx * wy;
        auto tapf = [&](const __half* q, float w) {
            union { float4 f; __half2 h[4]; } u4;
            u4.f = *(const float4*)q;
            const __half2 wh = __float2half2_rn(w);
            acc4[0] = __hfma2(wh, u4.h[0], acc4[0]);
            acc4[1] = __hfma2(wh, u4.h[1], acc4[1]);
            acc4[2] = __hfma2(wh, u4.h[2], acc4[2]);
            acc4[3] = __hfma2(wh, u4.h[3], acc4[3]);
        };
        tapf(tp, w00);
        tapf(tp + CF, w10);
        tapf(tp + PW * CF, w01);
        tapf(tp + PW * CF + CF, w11);
    }
    union { __half2 h[4]; f16x8 f; } uf;
    #pragma unroll
    for (int j = 0; j < 4; ++j) uf.h[j] = acc4[j];
    return uf.f;
}

constexpr float IS32_3 = 0.058925565098879624f;   // (1/sqrt(32)) / 3

// ============== split path: gather+MLP ==============
// r14: rgb/sig stores are now REGULAR (cached) — r13's nontemporal stores
// pushed 52MB straight to HBM and k_comp's nontemporal loads re-fetched it
// at full HBM latency (~50us hidden in "aux"). L2-resident handoff instead.
// Gather structure = r13 (p-outer, XCD partition, JIT weights, padded table).
constexpr int TG = 128;
constexpr int SLICE_A = 9216;   // per-wave LDS slice bytes
constexpr int SIGO = 5120;      // sigma region (float[64])

__global__ __launch_bounds__(TG)
void k_gmlpB(const __half2* __restrict__ pt, const float* __restrict__ coords,
             const float* __restrict__ w1, const float* __restrict__ b1,
             const float* __restrict__ w2, const float* __restrict__ b2,
             __half* __restrict__ rgbW, float* __restrict__ sigW)
{
    __shared__ __align__(16) char sm[2 * SLICE_A];   // 18.4 KB
    const int t = threadIdx.x;
    const int wv = t >> 6;
    const int l = t & 63;
    const int g = l >> 4;
    const int ln = l & 15;
    char* const slice = sm + wv * SLICE_A;

    // ---- XCD-partitioned block->sample mapping (r11) ----
    const int bid = blockIdx.x;                 // 6144 = 768 * 8
    const int xcd = bid & 7;
    const int nb = xcd >> 2;                    // XCDs 0-3: batch 0; 4-7: batch 1
    const int rank = (bid >> 3) * 4 + (xcd & 3);   // 0..3071 within batch
    const int waveBaseS = nb * (M_TOTAL / NB) + rank * TG + wv * 64;
    const __half* ptb = (const __half*)pt + (size_t)nb * 3 * (PTEX * CF);

    // ---- coords prefetch (4 independent triples) ----
    float cx[4], cy[4], cz[4];
    #pragma unroll
    for (int Mt = 0; Mt < 4; ++Mt) {
        const float* cp = coords + (size_t)(waveBaseS + 16 * Mt + ln) * 3;
        cx[Mt] = cp[0]; cy[Mt] = cp[1]; cz[Mt] = cp[2];
    }

    // ---- gather, p-OUTER (r13) ----
    __half2 acc[4][4];
    #pragma unroll
    for (int Mt = 0; Mt < 4; ++Mt)
        #pragma unroll
        for (int j = 0; j < 4; ++j) acc[Mt][j] = __float2half2_rn(0.f);

    #pragma unroll
    for (int p = 0; p < 3; ++p) {
        const __half* pp = ptb + (size_t)p * (PTEX * CF) + g * 8;
        #pragma unroll
        for (int Mt = 0; Mt < 4; ++Mt) {
            const float u = (p == 2) ? cz[Mt] : cx[Mt];
            const float v = (p == 0) ? cy[Mt] : ((p == 1) ? cz[Mt] : cx[Mt]);
            const float xf = fmaf(u, 128.f, 127.5f);
            const float yf = fmaf(v, 128.f, 127.5f);
            const float x0f = floorf(xf), y0f = floorf(yf);
            const float wx = xf - x0f, wy = yf - y0f;
            const int x0 = (int)x0f, y0 = (int)y0f;        // in [-1, 255]
            const int base = (y0 + 1) * PW + (x0 + 1);      // border handles OOB
            const __half* tp = pp + (size_t)base * CF;
            const float w00 = (1.f - wx) * (1.f - wy);
            const float w10 = wx * (1.f - wy);
            const float w01 = (1.f - wx) * wy;
            const float w11 = wx * wy;
            auto tapf = [&](const __half* q, float wq) {
                union { float4 f; __half2 h[4]; } u4;
                u4.f = *(const float4*)q;                   // lanes g=0..3 share one 64B line
                const __half2 wh = __float2half2_rn(wq);
                acc[Mt][0] = __hfma2(wh, u4.h[0], acc[Mt][0]);
                acc[Mt][1] = __hfma2(wh, u4.h[1], acc[Mt][1]);
                acc[Mt][2] = __hfma2(wh, u4.h[2], acc[Mt][2]);
                acc[Mt][3] = __hfma2(wh, u4.h[3], acc[Mt][3]);
            };
            tapf(tp, w00);
            tapf(tp + CF, w10);
            tapf(tp + PW * CF, w01);
            tapf(tp + PW * CF + CF, w11);
        }
    }

    f16x8 a1[4];
    #pragma unroll
    for (int Mt = 0; Mt < 4; ++Mt) {
        union { __half2 h[4]; f16x8 f; } uf;
        #pragma unroll
        for (int j = 0; j < 4; ++j) uf.h[j] = acc[Mt][j];
        a1[Mt] = uf.f;
    }

    // fence: keep weight loads OUT of the gather region (live-range control)
    __builtin_amdgcn_sched_barrier(0);

    // ---- layer 1: load w1 fragments just-in-time, then MFMA -> h in LDS ----
    f16x8 b1f[4];
    float b1v[4];
    #pragma unroll
    for (int Nt = 0; Nt < 4; ++Nt) {
        const int hn = 16 * Nt + ln;
        const float4* p0 = (const float4*)(w1 + hn * CF + g * 8);
        float4 u = p0[0], v = p0[1];
        b1f[Nt][0] = (_Float16)u.x; b1f[Nt][1] = (_Float16)u.y;
        b1f[Nt][2] = (_Float16)u.z; b1f[Nt][3] = (_Float16)u.w;
        b1f[Nt][4] = (_Float16)v.x; b1f[Nt][5] = (_Float16)v.y;
        b1f[Nt][6] = (_Float16)v.z; b1f[Nt][7] = (_Float16)v.w;
        b1v[Nt] = b1[hn];
    }

    #pragma unroll
    for (int Nt = 0; Nt < 4; ++Nt) {
        f32x4 d0 = {0.f, 0.f, 0.f, 0.f};
        f32x4 d1 = {0.f, 0.f, 0.f, 0.f};
        f32x4 d2 = {0.f, 0.f, 0.f, 0.f};
        f32x4 d3 = {0.f, 0.f, 0.f, 0.f};
        d0 = __builtin_amdgcn_mfma_f32_16x16x32_f16(a1[0], b1f[Nt], d0, 0, 0, 0);
        d1 = __builtin_amdgcn_mfma_f32_16x16x32_f16(a1[1], b1f[Nt], d1, 0, 0, 0);
        d2 = __builtin_amdgcn_mfma_f32_16x16x32_f16(a1[2], b1f[Nt], d2, 0, 0, 0);
        d3 = __builtin_amdgcn_mfma_f32_16x16x32_f16(a1[3], b1f[Nt], d3, 0, 0, 0);
        const int hcol = 16 * Nt + ln;
        #pragma unroll
        for (int Mt = 0; Mt < 4; ++Mt) {
            f32x4 dd = (Mt == 0) ? d0 : (Mt == 1) ? d1 : (Mt == 2) ? d2 : d3;
            #pragma unroll
            for (int r = 0; r < 4; ++r) {
                const float hv = softplus_f(fmaf(dd[r], IS32_3, b1v[Nt]));
                const int row = 16 * Mt + 4 * g + r;
                *(__half*)(slice + row * 144 + hcol * 2) = __float2half(hv);
            }
        }
    }

    // ---- layer-2 A-fragments (h transposed via LDS) ----
    f16x8 a2[4][2];
    #pragma unroll
    for (int Mt = 0; Mt < 4; ++Mt)
        #pragma unroll
        for (int kh = 0; kh < 2; ++kh)
            a2[Mt][kh] = *(const f16x8*)(slice + (16 * Mt + ln) * 144 + (kh * 4 + g) * 16);

    // ---- layer 2: w2 fragments loaded just-in-time inside the loop ----
    #pragma unroll
    for (int Nt2 = 0; Nt2 < 3; ++Nt2) {
        const int o = 16 * Nt2 + ln;
        f16x8 f0, f1;
        float bv;
        if (o < 33) {
            const float4* p0 = (const float4*)(w2 + o * HID + g * 8);
            float4 u = p0[0], v = p0[1];
            f0[0] = (_Float16)u.x; f0[1] = (_Float16)u.y;
            f0[2] = (_Float16)u.z; f0[3] = (_Float16)u.w;
            f0[4] = (_Float16)v.x; f0[5] = (_Float16)v.y;
            f0[6] = (_Float16)v.z; f0[7] = (_Float16)v.w;
            const float4* p1 = (const float4*)(w2 + o * HID + 32 + g * 8);
            float4 u1 = p1[0], v1 = p1[1];
            f1[0] = (_Float16)u1.x; f1[1] = (_Float16)u1.y;
            f1[2] = (_Float16)u1.z; f1[3] = (_Float16)u1.w;
            f1[4] = (_Float16)v1.x; f1[5] = (_Float16)v1.y;
            f1[6] = (_Float16)v1.z; f1[7] = (_Float16)v1.w;
            bv = b2[o];
        } else {
            #pragma unroll
            for (int i = 0; i < 8; ++i) { f0[i] = (_Float16)0.f; f1[i] = (_Float16)0.f; }
            bv = 0.f;
        }
        f32x4 e0 = {0.f, 0.f, 0.f, 0.f};
        f32x4 e1 = {0.f, 0.f, 0.f, 0.f};
        f32x4 e2 = {0.f, 0.f, 0.f, 0.f};
        f32x4 e3 = {0.f, 0.f, 0.f, 0.f};
        e0 = __builtin_amdgcn_mfma_f32_16x16x32_f16(a2[0][0], f0, e0, 0, 0, 0);
        e1 = __builtin_amdgcn_mfma_f32_16x16x32_f16(a2[1][0], f0, e1, 0, 0, 0);
        e2 = __builtin_amdgcn_mfma_f32_16x16x32_f16(a2[2][0], f0, e2, 0, 0, 0);
        e3 = __builtin_amdgcn_mfma_f32_16x16x32_f16(a2[3][0], f0, e3, 0, 0, 0);
        e0 = __builtin_amdgcn_mfma_f32_16x16x32_f16(a2[0][1], f1, e0, 0, 0, 0);
        e1 = __builtin_amdgcn_mfma_f32_16x16x32_f16(a2[1][1], f1, e1, 0, 0, 0);
        e2 = __builtin_amdgcn_mfma_f32_16x16x32_f16(a2[2][1], f1, e2, 0, 0, 0);
        e3 = __builtin_amdgcn_mfma_f32_16x16x32_f16(a2[3][1], f1, e3, 0, 0, 0);
        if (o == 0) {
            #pragma unroll
            for (int Mt = 0; Mt < 4; ++Mt) {
                f32x4 ee = (Mt == 0) ? e0 : (Mt == 1) ? e1 : (Mt == 2) ? e2 : e3;
                #pragma unroll
                for (int r = 0; r < 4; ++r) {
                    const int row = 16 * Mt + 4 * g + r;
                    *(float*)(slice + SIGO + row * 4) = fmaf(ee[r], 0.125f, bv);
                }
            }
        } else if (o < 33) {
            #pragma unroll
            for (int Mt = 0; Mt < 4; ++Mt) {
                f32x4 ee = (Mt == 0) ? e0 : (Mt == 1) ? e1 : (Mt == 2) ? e2 : e3;
                #pragma unroll
                for (int r = 0; r < 4; ++r) {
                    const float vv = fmaf(ee[r], 0.125f, bv);
                    const float rr = sigmoid_f(vv) * 1.002f - 0.001f;
                    const int row = 16 * Mt + 4 * g + r;
                    *(__half*)(slice + row * 80 + (o - 1) * 2) = __float2half(rr);
                }
            }
        }
    }

    // ---- coalesced REGULAR stores of rgb + sigma (L2-resident handoff) ----
    const int q0 = l & 3, r0 = l >> 2;
    #pragma unroll
    for (int q = 0; q < 4; ++q) {
        const int row = 16 * q + r0;
        i32x4 v = *(const i32x4*)(slice + row * 80 + q0 * 16);
        *(i32x4*)((char*)rgbW + (size_t)(waveBaseS + row) * 64 + q0 * 16) = v;
    }
    sigW[waveBaseS + l] = *(const float*)(slice + SIGO + l * 4);
}

// ============== split path: composite ==============
// r14: regular (cached) loads + chunked depth-8 prefetch — r13's nontemporal
// depth-1 loads serialized ~95 HBM latencies per thread (~50us kernel).
__global__ __launch_bounds__(512)
void k_comp(const __half* __restrict__ rgbW, const float* __restrict__ sigW,
            const float* __restrict__ depths, float* __restrict__ out)
{
    __shared__ float sgS[16 * SAMP];
    __shared__ float dpS[16 * SAMP];
    const int t = threadIdx.x;
    const int rayBase = blockIdx.x * 16;
    for (int i = t; i < 16 * SAMP; i += 512) {
        sgS[i] = sigW[(size_t)rayBase * SAMP + i];
        dpS[i] = depths[(size_t)rayBase * SAMP + i];
    }
    __syncthreads();

    const int rs = t >> 5;          // ray slot 0..15
    const int c = t & 31;           // channel
    const size_t mb = (size_t)(rayBase + rs) * SAMP;
    const __half* rgbp = rgbW + mb * 32 + c;

    float T = 1.f, a_out = 0.f;
    float sp = sgS[rs * SAMP], dp = dpS[rs * SAMP];
    float rp = __half2float(rgbp[0]);

    for (int chk = 0; chk < 12; ++chk) {
        const int sbeg = chk * 8 + 1;              // first mid-index in chunk
        __half h[8];
        #pragma unroll
        for (int j = 0; j < 8; ++j) {
            const int ss = min(sbeg + j, SAMP - 1);
            h[j] = rgbp[(size_t)ss * 32];          // 8 independent loads in flight
        }
        #pragma unroll
        for (int j = 0; j < 8; ++j) {
            const int ss = sbeg + j;
            if (ss >= SAMP) break;                 // uniform; last chunk only
            const float rc = __half2float(h[j]);
            const float sc = sgS[rs * SAMP + ss];
            const float dc = dpS[rs * SAMP + ss];
            const float dens = softplus_f(0.5f * (sp + sc) - 1.f);
            const float alpha = 1.f - __expf(-(dc - dp) * dens);
            a_out = fmaf(alpha * T, 0.5f * (rp + rc), a_out);
            T *= 1.f - alpha + 1e-10f;
            sp = sc; dp = dc; rp = rc;
        }
    }
    out[(size_t)(rayBase + rs) * CF + c] = fmaf(a_out, 2.f, -1.f);
}

// ============== fallback: direct from planes (no workspace) ==============
constexpr int THREADS = 384;
constexpr int SLICE = 9216;
constexpr int SIG_OFF = 5120;
constexpr int DEP_OFF = 5376;

__device__ __forceinline__ void mlp_slice(char* slice, const f16x8 a1[4],
                                          const Wreg& w, int g, int ln) {
    #pragma unroll
    for (int Nt = 0; Nt < 4; ++Nt) {
        f32x4 d0 = {0.f, 0.f, 0.f, 0.f};
        f32x4 d1 = {0.f, 0.f, 0.f, 0.f};
        f32x4 d2 = {0.f, 0.f, 0.f, 0.f};
        f32x4 d3 = {0.f, 0.f, 0.f, 0.f};
        d0 = __builtin_amdgcn_mfma_f32_16x16x32_f16(a1[0], w.b1f[Nt], d0, 0, 0, 0);
        d1 = __builtin_amdgcn_mfma_f32_16x16x32_f16(a1[1], w.b1f[Nt], d1, 0, 0, 0);
        d2 = __builtin_amdgcn_mfma_f32_16x16x32_f16(a1[2], w.b1f[Nt], d2, 0, 0, 0);
        d3 = __builtin_amdgcn_mfma_f32_16x16x32_f16(a1[3], w.b1f[Nt], d3, 0, 0, 0);
        const int hcol = 16 * Nt + ln;
        #pragma unroll
        for (int Mt = 0; Mt < 4; ++Mt) {
            f32x4 dd = (Mt == 0) ? d0 : (Mt == 1) ? d1 : (Mt == 2) ? d2 : d3;
            #pragma unroll
            for (int r = 0; r < 4; ++r) {
                const float hv = softplus_f(fmaf(dd[r], IS32_3, w.b1v[Nt]));
                const int row = 16 * Mt + 4 * g + r;
                *(__half*)(slice + row * 144 + hcol * 2) = __float2half(hv);
            }
        }
    }

    f16x8 a2[4][2];
    #pragma unroll
    for (int Mt = 0; Mt < 4; ++Mt)
        #pragma unroll
        for (int kh = 0; kh < 2; ++kh)
            a2[Mt][kh] = *(const f16x8*)(slice + (16 * Mt + ln) * 144 + (kh * 4 + g) * 16);

    #pragma unroll
    for (int Nt2 = 0; Nt2 < 3; ++Nt2) {
        f32x4 e0 = {0.f, 0.f, 0.f, 0.f};
        f32x4 e1 = {0.f, 0.f, 0.f, 0.f};
        f32x4 e2 = {0.f, 0.f, 0.f, 0.f};
        f32x4 e3 = {0.f, 0.f, 0.f, 0.f};
        #pragma unroll
        for (int kh = 0; kh < 2; ++kh) {
            e0 = __builtin_amdgcn_mfma_f32_16x16x32_f16(a2[0][kh], w.b2f[Nt2][kh], e0, 0, 0, 0);
            e1 = __builtin_amdgcn_mfma_f32_16x16x32_f16(a2[1][kh], w.b2f[Nt2][kh], e1, 0, 0, 0);
            e2 = __builtin_amdgcn_mfma_f32_16x16x32_f16(a2[2][kh], w.b2f[Nt2][kh], e2, 0, 0, 0);
            e3 = __builtin_amdgcn_mfma_f32_16x16x32_f16(a2[3][kh], w.b2f[Nt2][kh], e3, 0, 0, 0);
        }
        const int o = 16 * Nt2 + ln;
        if (o == 0) {
            #pragma unroll
            for (int Mt = 0; Mt < 4; ++Mt) {
                f32x4 ee = (Mt == 0) ? e0 : (Mt == 1) ? e1 : (Mt == 2) ? e2 : e3;
                #pragma unroll
                for (int r = 0; r < 4; ++r) {
                    const int row = 16 * Mt + 4 * g + r;
                    *(float*)(slice + SIG_OFF + row * 4) = fmaf(ee[r], 0.125f, w.b2v[0]);
                }
            }
        } else if (o < 33) {
            #pragma unroll
            for (int Mt = 0; Mt < 4; ++Mt) {
                f32x4 ee = (Mt == 0) ? e0 : (Mt == 1) ? e1 : (Mt == 2) ? e2 : e3;
                #pragma unroll
                for (int r = 0; r < 4; ++r) {
                    const float vv = fmaf(ee[r], 0.125f, w.b2v[Nt2]);
                    const float rr = sigmoid_f(vv) * 1.002f - 0.001f;
                    const int row = 16 * Mt + 4 * g + r;
                    *(__half*)(slice + row * 80 + (o - 1) * 2) = __float2half(rr);
                }
            }
        }
    }
}

__global__ __launch_bounds__(THREADS)
void k_fused(const float* __restrict__ planes,
             const float* __restrict__ coords, const float* __restrict__ depths,
             const float* __restrict__ w1, const float* __restrict__ b1,
             const float* __restrict__ w2, const float* __restrict__ b2,
             float* __restrict__ out)
{
    __shared__ __align__(16) char sm[6 * SLICE];
    const int t = threadIdx.x;
    const int wv = t >> 6;
    const int l = t & 63;
    const int g = l >> 4;
    const int ln = l & 15;
    char* const slice = sm + wv * SLICE;

    const int msamp = blockIdx.x * THREADS + t;
    const int nb = (msamp >= M_TOTAL / NB) ? 1 : 0;

    Wreg w;
    load_weights(w, w1, b1, w2, b2, g, ln);

    const float* cp = coords + (size_t)msamp * 3;
    const float c0 = cp[0], c1 = cp[1], c2v = cp[2];
    const float myDep = depths[msamp];

    float xf32[CF];
    #pragma unroll
    for (int c = 0; c < CF; ++c) xf32[c] = 0.f;

    #pragma unroll
    for (int p = 0; p < 3; ++p) {
        const float u = (p == 2) ? c2v : c0;
        const float v = (p == 0) ? c1 : ((p == 1) ? c2v : c0);
        const float xf = fmaf(u, 128.f, 127.5f);
        const float yf = fmaf(v, 128.f, 127.5f);
        const float x0f = floorf(xf), y0f = floorf(yf);
        const float wx = xf - x0f, wy = yf - y0f;
        const int x0 = (int)x0f, y0 = (int)y0f;
        const float vx0 = (x0 >= 0 && x0 < HW) ? 1.f : 0.f;
        const float vx1 = (x0 + 1 >= 0 && x0 + 1 < HW) ? 1.f : 0.f;
        const float vy0 = (y0 >= 0 && y0 < HW) ? 1.f : 0.f;
        const float vy1 = (y0 + 1 >= 0 && y0 + 1 < HW) ? 1.f : 0.f;
        const int xc0 = min(max(x0, 0), HW - 1), xc1 = min(max(x0 + 1, 0), HW - 1);
        const int yc0 = min(max(y0, 0), HW - 1), yc1 = min(max(y0 + 1, 0), HW - 1);
        const float w00 = (1.f - wx) * (1.f - wy) * vx0 * vy0;
        const float w10 = wx * (1.f - wy) * vx1 * vy0;
        const float w01 = (1.f - wx) * wy * vx0 * vy1;
        const float w11 = wx * wy * vx1 * vy1;

        const float* pb = planes + (((size_t)(nb * 3 + p) * CF) << 16);
        const int i00 = yc0 * HW + xc0, i10 = yc0 * HW + xc1;
        const int i01 = yc1 * HW + xc0, i11 = yc1 * HW + xc1;
        #pragma unroll
        for (int c = 0; c < CF; ++c) {
            const float* pc = pb + ((size_t)c << 16);
            float a0 = fmaf(w00, pc[i00], fmaf(w10, pc[i10], 0.f));
            float a1v = fmaf(w01, pc[i01], fmaf(w11, pc[i11], 0.f));
            xf32[c] += a0 + a1v;
        }
    }

    #pragma unroll
    for (int c = 0; c < 4; ++c) {
        union { __half2 h[4]; i32x4 v; } u4;
        #pragma unroll
        for (int j = 0; j < 4; ++j)
            u4.h[j] = __floats2half2_rn(xf32[8 * c + 2 * j], xf32[8 * c + 2 * j + 1]);
        *(i32x4*)(slice + l * 80 + c * 16) = u4.v;
    }

    f16x8 a1[4];
    #pragma unroll
    for (int Mt = 0; Mt < 4; ++Mt)
        a1[Mt] = *(const f16x8*)(slice + (16 * Mt + ln) * 80 + g * 16);

    mlp_slice(slice, a1, w, g, ln);
    *(float*)(slice + DEP_OFF + l * 4) = myDep;

    __syncthreads();

    if (t < 128) {
        const int crl = t >> 5;
        const int c = t & 31;
        const int bs = crl * SAMP;
        auto sigAt = [&](int sb) -> float {
            return *(const float*)(sm + (sb >> 6) * SLICE + SIG_OFF + (sb & 63) * 4);
        };
        auto depAt = [&](int sb) -> float {
            return *(const float*)(sm + (sb >> 6) * SLICE + DEP_OFF + (sb & 63) * 4);
        };
        auto rgbAt = [&](int sb) -> float {
            return __half2float(*(const __half*)(sm + (sb >> 6) * SLICE + (sb & 63) * 80 + c * 2));
        };
        float T = 1.f, a_out = 0.f;
        float sp = sigAt(bs), dp = depAt(bs), rp = rgbAt(bs);
        for (int ss = 1; ss < SAMP; ++ss) {
            const float sc = sigAt(bs + ss);
            const float dc = depAt(bs + ss);
            const float rc = rgbAt(bs + ss);
            const float dens = softplus_f(0.5f * (sp + sc) - 1.f);
            const float alpha = 1.f - __expf(-(dc - dp) * dens);
            a_out = fmaf(alpha * T, 0.5f * (rp + rc), a_out);
            T *= 1.f - alpha + 1e-10f;
            sp = sc; dp = dc; rp = rc;
        }
        out[(size_t)(blockIdx.x * 4 + crl) * CF + c] = fmaf(a_out, 2.f, -1.f);
    }
}

extern "C" void kernel_launch(void* const* d_in, const int* in_sizes, int n_in,
                              void* d_out, int out_size, void* d_ws, size_t ws_size,
                              hipStream_t stream) {
    (void)in_sizes; (void)n_in; (void)out_size;
    const float* planes = (const float*)d_in[0];
    const float* coords = (const float*)d_in[1];
    const float* depths = (const float*)d_in[2];
    const float* w1 = (const float*)d_in[3];
    const float* b1 = (const float*)d_in[4];
    const float* w2 = (const float*)d_in[5];
    const float* b2 = (const float*)d_in[6];
    float* out = (float*)d_out;

    const size_t ptBytes  = (size_t)NB * 3 * PTEX * CF * sizeof(__half);   // 25.56 MB
    const size_t rgbBytes = (size_t)M_TOTAL * CF * sizeof(__half);         // 50.33 MB
    const size_t sigBytes = (size_t)M_TOTAL * sizeof(float);               //  3.15 MB

    dim3 tgrid((PTEX + 255) / 256, NB * 3);   // (261, 6)

    if (ws_size >= ptBytes + rgbBytes + sigBytes) {
        __half2* pt = (__half2*)d_ws;
        __half* rgbW = (__half*)((char*)d_ws + ptBytes);
        float* sigW = (float*)((char*)d_ws + ptBytes + rgbBytes);
        k_transposeB<<<tgrid, 256, 0, stream>>>(planes, pt);
        k_gmlpB<<<M_TOTAL / TG, TG, 0, stream>>>(pt, coords, w1, b1, w2, b2, rgbW, sigW);
        k_comp<<<NB * RAYS / 16, 512, 0, stream>>>(rgbW, sigW, depths, out);
    } else {
        k_fused<<<M_TOTAL / THREADS, THREADS, 0, stream>>>(planes, coords, depths,
                                                           w1, b1, w2, b2, out);
    }
}

// Round 15
// 145.902 us; speedup vs baseline: 1.3333x; 1.0104x over previous
//
#include <hip/hip_runtime.h>
#include <hip/hip_fp16.h>

#define NB 2
#define RAYS 4096
#define SAMP 96
#define CF 32
#define HID 64
#define HW 256
#define PW 258                  // padded plane width (1-texel zero border)
#define PTEX (PW * PW)          // 66564 texels per plane

constexpr int M_TOTAL = NB * RAYS * SAMP;   // 786432 samples

typedef _Float16 f16x8 __attribute__((ext_vector_type(8)));
typedef float f32x4 __attribute__((ext_vector_type(4)));
typedef int i32x4 __attribute__((ext_vector_type(4)));

__device__ __forceinline__ float softplus_f(float z) {
    return fmaxf(z, 0.f) + __logf(1.f + __expf(-fabsf(z)));
}
__device__ __forceinline__ float sigmoid_f(float z) {
    return __fdividef(1.f, 1.f + __expf(-z));
}

// planes (N,3,C,256,256) f32 -> pt (N*3, 258, 258, C) f16, zero border.
__global__ __launch_bounds__(256)
void k_transposeB(const float* __restrict__ src, __half2* __restrict__ dst) {
    const int xy = blockIdx.x * 256 + threadIdx.x;
    const int pn = blockIdx.y;                    // n*3+p in [0,6)
    if (xy >= PTEX) return;
    const int y = xy / PW;
    const int x = xy - y * PW;
    __half2 v[16];
    if (x >= 1 && x <= HW && y >= 1 && y <= HW) {
        const float* s = src + (((size_t)pn * CF) << 16) + (y - 1) * HW + (x - 1);
        #pragma unroll
        for (int c2 = 0; c2 < 16; ++c2) {
            const float a = s[((size_t)(2 * c2)) << 16];
            const float b = s[((size_t)(2 * c2 + 1)) << 16];
            v[c2] = __floats2half2_rn(a, b);
        }
    } else {
        #pragma unroll
        for (int c2 = 0; c2 < 16; ++c2) v[c2] = __float2half2_rn(0.f);
    }
    __half2* d = dst + ((size_t)pn * PTEX + xy) * 16;
    #pragma unroll
    for (int q = 0; q < 4; ++q)
        ((i32x4*)d)[q] = ((const i32x4*)v)[q];
}

// ---- shared device pieces (fallback path) ----
struct Wreg {
    f16x8 b1f[4];  float b1v[4];
    f16x8 b2f[3][2]; float b2v[3];
};

__device__ __forceinline__ void load_weights(Wreg& w,
        const float* __restrict__ w1, const float* __restrict__ b1,
        const float* __restrict__ w2, const float* __restrict__ b2,
        int g, int ln) {
    #pragma unroll
    for (int Nt = 0; Nt < 4; ++Nt) {
        const int hn = 16 * Nt + ln;
        const float4* p0 = (const float4*)(w1 + hn * CF + g * 8);
        float4 u = p0[0], v = p0[1];
        w.b1f[Nt][0] = (_Float16)u.x; w.b1f[Nt][1] = (_Float16)u.y;
        w.b1f[Nt][2] = (_Float16)u.z; w.b1f[Nt][3] = (_Float16)u.w;
        w.b1f[Nt][4] = (_Float16)v.x; w.b1f[Nt][5] = (_Float16)v.y;
        w.b1f[Nt][6] = (_Float16)v.z; w.b1f[Nt][7] = (_Float16)v.w;
        w.b1v[Nt] = b1[hn];
    }
    #pragma unroll
    for (int Nt2 = 0; Nt2 < 3; ++Nt2) {
        const int o = 16 * Nt2 + ln;
        if (o < 33) {
            #pragma unroll
            for (int kh = 0; kh < 2; ++kh) {
                const float4* p0 = (const float4*)(w2 + o * HID + kh * 32 + g * 8);
                float4 u = p0[0], v = p0[1];
                w.b2f[Nt2][kh][0] = (_Float16)u.x; w.b2f[Nt2][kh][1] = (_Float16)u.y;
                w.b2f[Nt2][kh][2] = (_Float16)u.z; w.b2f[Nt2][kh][3] = (_Float16)u.w;
                w.b2f[Nt2][kh][4] = (_Float16)v.x; w.b2f[Nt2][kh][5] = (_Float16)v.y;
                w.b2f[Nt2][kh][6] = (_Float16)v.z; w.b2f[Nt2][kh][7] = (_Float16)v.w;
            }
            w.b2v[Nt2] = b2[o];
        } else {
            #pragma unroll
            for (int kh = 0; kh < 2; ++kh)
                #pragma unroll
                for (int i = 0; i < 8; ++i) w.b2f[Nt2][kh][i] = (_Float16)0.f;
            w.b2v[Nt2] = 0.f;
        }
    }
}

// 4-lane cooperative gather (fallback path)
__device__ __forceinline__ f16x8 gather4(const __half* __restrict__ ptb,
                                         float c0, float c1, float c2v, int g) {
    __half2 acc4[4];
    #pragma unroll
    for (int j = 0; j < 4; ++j) acc4[j] = __float2half2_rn(0.f);

    #pragma unroll
    for (int p = 0; p < 3; ++p) {
        const float u = (p == 2) ? c2v : c0;
        const float v = (p == 0) ? c1 : ((p == 1) ? c2v : c0);
        const float xf = fmaf(u, 128.f, 127.5f);
        const float yf = fmaf(v, 128.f, 127.5f);
        const float x0f = floorf(xf), y0f = floorf(yf);
        const float wx = xf - x0f, wy = yf - y0f;
        const int x0 = (int)x0f, y0 = (int)y0f;
        const int base = (y0 + 1) * PW + (x0 + 1);
        const __half* tp = ptb + (size_t)p * (PTEX * CF) + (size_t)base * CF + g * 8;
        const float w00 = (1.f - wx) * (1.f - wy);
        const float w10 = wx * (1.f - wy);
        const float w01 = (1.f - wx) * wy;
        const float w11 = wx * wy;
        auto tapf = [&](const __half* q, float w) {
            union { float4 f; __half2 h[4]; } u4;
            u4.f = *(const float4*)q;
            const __half2 wh = __float2half2_rn(w);
            acc4[0] = __hfma2(wh, u4.h[0], acc4[0]);
            acc4[1] = __hfma2(wh, u4.h[1], acc4[1]);
            acc4[2] = __hfma2(wh, u4.h[2], acc4[2]);
            acc4[3] = __hfma2(wh, u4.h[3], acc4[3]);
        };
        tapf(tp, w00);
        tapf(tp + CF, w10);
        tapf(tp + PW * CF, w01);
        tapf(tp + PW * CF + CF, w11);
    }
    union { __half2 h[4]; f16x8 f; } uf;
    #pragma unroll
    for (int j = 0; j < 4; ++j) uf.h[j] = acc4[j];
    return uf.f;
}

constexpr float IS32_3 = 0.058925565098879624f;   // (1/sqrt(32)) / 3

// ============== split path: gather+MLP ==============
// r15: BATCH-ISSUED taps. Per plane-phase, compute all 4 Mt addresses first,
// then issue all 16 tap loads into explicit float4 tv[16] (64 VGPRs of load
// data in flight), THEN consume. Little's law: r14 had ~10 loads in flight
// per wave (68 VGPR, immediate consume) -> 2.9 TB/s; doubling in-flight
// should push toward 4.5-5 TB/s. Deliberate VGPR-for-MLP trade.
constexpr int TG = 128;
constexpr int SLICE_A = 9216;   // per-wave LDS slice bytes
constexpr int SIGO = 5120;      // sigma region (float[64])

__global__ __launch_bounds__(TG)
void k_gmlpB(const __half2* __restrict__ pt, const float* __restrict__ coords,
             const float* __restrict__ w1, const float* __restrict__ b1,
             const float* __restrict__ w2, const float* __restrict__ b2,
             __half* __restrict__ rgbW, float* __restrict__ sigW)
{
    __shared__ __align__(16) char sm[2 * SLICE_A];   // 18.4 KB
    const int t = threadIdx.x;
    const int wv = t >> 6;
    const int l = t & 63;
    const int g = l >> 4;
    const int ln = l & 15;
    char* const slice = sm + wv * SLICE_A;

    // ---- XCD-partitioned block->sample mapping (r11) ----
    const int bid = blockIdx.x;                 // 6144 = 768 * 8
    const int xcd = bid & 7;
    const int nb = xcd >> 2;                    // XCDs 0-3: batch 0; 4-7: batch 1
    const int rank = (bid >> 3) * 4 + (xcd & 3);   // 0..3071 within batch
    const int waveBaseS = nb * (M_TOTAL / NB) + rank * TG + wv * 64;
    const __half* ptb = (const __half*)pt + (size_t)nb * 3 * (PTEX * CF);

    // ---- coords prefetch (4 independent triples) ----
    float cx[4], cy[4], cz[4];
    #pragma unroll
    for (int Mt = 0; Mt < 4; ++Mt) {
        const float* cp = coords + (size_t)(waveBaseS + 16 * Mt + ln) * 3;
        cx[Mt] = cp[0]; cy[Mt] = cp[1]; cz[Mt] = cp[2];
    }

    // ---- gather, p-OUTER, batch-issued taps ----
    __half2 acc[4][4];
    #pragma unroll
    for (int Mt = 0; Mt < 4; ++Mt)
        #pragma unroll
        for (int j = 0; j < 4; ++j) acc[Mt][j] = __float2half2_rn(0.f);

    #pragma unroll
    for (int p = 0; p < 3; ++p) {
        const __half* pp = ptb + (size_t)p * (PTEX * CF) + g * 8;
        const __half* tp[4];
        float w00[4], w10[4], w01[4], w11[4];
        #pragma unroll
        for (int Mt = 0; Mt < 4; ++Mt) {
            const float u = (p == 2) ? cz[Mt] : cx[Mt];
            const float v = (p == 0) ? cy[Mt] : ((p == 1) ? cz[Mt] : cx[Mt]);
            const float xf = fmaf(u, 128.f, 127.5f);
            const float yf = fmaf(v, 128.f, 127.5f);
            const float x0f = floorf(xf), y0f = floorf(yf);
            const float wx = xf - x0f, wy = yf - y0f;
            const int x0 = (int)x0f, y0 = (int)y0f;        // in [-1, 255]
            const int base = (y0 + 1) * PW + (x0 + 1);      // border handles OOB
            tp[Mt] = pp + (size_t)base * CF;
            w00[Mt] = (1.f - wx) * (1.f - wy);
            w10[Mt] = wx * (1.f - wy);
            w01[Mt] = (1.f - wx) * wy;
            w11[Mt] = wx * wy;
        }
        // issue all 16 loads before any consume (lanes g=0..3 share 64B lines)
        float4 tv[16];
        #pragma unroll
        for (int Mt = 0; Mt < 4; ++Mt) {
            tv[Mt * 4 + 0] = *(const float4*)(tp[Mt]);
            tv[Mt * 4 + 1] = *(const float4*)(tp[Mt] + CF);
            tv[Mt * 4 + 2] = *(const float4*)(tp[Mt] + PW * CF);
            tv[Mt * 4 + 3] = *(const float4*)(tp[Mt] + PW * CF + CF);
        }
        #pragma unroll
        for (int Mt = 0; Mt < 4; ++Mt) {
            auto fma4 = [&](float4 f, float wq) {
                union { float4 ff; __half2 h[4]; } u4;
                u4.ff = f;
                const __half2 wh = __float2half2_rn(wq);
                acc[Mt][0] = __hfma2(wh, u4.h[0], acc[Mt][0]);
                acc[Mt][1] = __hfma2(wh, u4.h[1], acc[Mt][1]);
                acc[Mt][2] = __hfma2(wh, u4.h[2], acc[Mt][2]);
                acc[Mt][3] = __hfma2(wh, u4.h[3], acc[Mt][3]);
            };
            fma4(tv[Mt * 4 + 0], w00[Mt]);
            fma4(tv[Mt * 4 + 1], w10[Mt]);
            fma4(tv[Mt * 4 + 2], w01[Mt]);
            fma4(tv[Mt * 4 + 3], w11[Mt]);
        }
    }

    f16x8 a1[4];
    #pragma unroll
    for (int Mt = 0; Mt < 4; ++Mt) {
        union { __half2 h[4]; f16x8 f; } uf;
        #pragma unroll
        for (int j = 0; j < 4; ++j) uf.h[j] = acc[Mt][j];
        a1[Mt] = uf.f;
    }

    // fence: keep weight loads OUT of the gather region (live-range control)
    __builtin_amdgcn_sched_barrier(0);

    // ---- layer 1: load w1 fragments just-in-time, then MFMA -> h in LDS ----
    f16x8 b1f[4];
    float b1v[4];
    #pragma unroll
    for (int Nt = 0; Nt < 4; ++Nt) {
        const int hn = 16 * Nt + ln;
        const float4* p0 = (const float4*)(w1 + hn * CF + g * 8);
        float4 u = p0[0], v = p0[1];
        b1f[Nt][0] = (_Float16)u.x; b1f[Nt][1] = (_Float16)u.y;
        b1f[Nt][2] = (_Float16)u.z; b1f[Nt][3] = (_Float16)u.w;
        b1f[Nt][4] = (_Float16)v.x; b1f[Nt][5] = (_Float16)v.y;
        b1f[Nt][6] = (_Float16)v.z; b1f[Nt][7] = (_Float16)v.w;
        b1v[Nt] = b1[hn];
    }

    #pragma unroll
    for (int Nt = 0; Nt < 4; ++Nt) {
        f32x4 d0 = {0.f, 0.f, 0.f, 0.f};
        f32x4 d1 = {0.f, 0.f, 0.f, 0.f};
        f32x4 d2 = {0.f, 0.f, 0.f, 0.f};
        f32x4 d3 = {0.f, 0.f, 0.f, 0.f};
        d0 = __builtin_amdgcn_mfma_f32_16x16x32_f16(a1[0], b1f[Nt], d0, 0, 0, 0);
        d1 = __builtin_amdgcn_mfma_f32_16x16x32_f16(a1[1], b1f[Nt], d1, 0, 0, 0);
        d2 = __builtin_amdgcn_mfma_f32_16x16x32_f16(a1[2], b1f[Nt], d2, 0, 0, 0);
        d3 = __builtin_amdgcn_mfma_f32_16x16x32_f16(a1[3], b1f[Nt], d3, 0, 0, 0);
        const int hcol = 16 * Nt + ln;
        #pragma unroll
        for (int Mt = 0; Mt < 4; ++Mt) {
            f32x4 dd = (Mt == 0) ? d0 : (Mt == 1) ? d1 : (Mt == 2) ? d2 : d3;
            #pragma unroll
            for (int r = 0; r < 4; ++r) {
                const float hv = softplus_f(fmaf(dd[r], IS32_3, b1v[Nt]));
                const int row = 16 * Mt + 4 * g + r;
                *(__half*)(slice + row * 144 + hcol * 2) = __float2half(hv);
            }
        }
    }

    // ---- layer-2 A-fragments (h transposed via LDS) ----
    f16x8 a2[4][2];
    #pragma unroll
    for (int Mt = 0; Mt < 4; ++Mt)
        #pragma unroll
        for (int kh = 0; kh < 2; ++kh)
            a2[Mt][kh] = *(const f16x8*)(slice + (16 * Mt + ln) * 144 + (kh * 4 + g) * 16);

    // ---- layer 2: w2 fragments loaded just-in-time inside the loop ----
    #pragma unroll
    for (int Nt2 = 0; Nt2 < 3; ++Nt2) {
        const int o = 16 * Nt2 + ln;
        f16x8 f0, f1;
        float bv;
        if (o < 33) {
            const float4* p0 = (const float4*)(w2 + o * HID + g * 8);
            float4 u = p0[0], v = p0[1];
            f0[0] = (_Float16)u.x; f0[1] = (_Float16)u.y;
            f0[2] = (_Float16)u.z; f0[3] = (_Float16)u.w;
            f0[4] = (_Float16)v.x; f0[5] = (_Float16)v.y;
            f0[6] = (_Float16)v.z; f0[7] = (_Float16)v.w;
            const float4* p1 = (const float4*)(w2 + o * HID + 32 + g * 8);
            float4 u1 = p1[0], v1 = p1[1];
            f1[0] = (_Float16)u1.x; f1[1] = (_Float16)u1.y;
            f1[2] = (_Float16)u1.z; f1[3] = (_Float16)u1.w;
            f1[4] = (_Float16)v1.x; f1[5] = (_Float16)v1.y;
            f1[6] = (_Float16)v1.z; f1[7] = (_Float16)v1.w;
            bv = b2[o];
        } else {
            #pragma unroll
            for (int i = 0; i < 8; ++i) { f0[i] = (_Float16)0.f; f1[i] = (_Float16)0.f; }
            bv = 0.f;
        }
        f32x4 e0 = {0.f, 0.f, 0.f, 0.f};
        f32x4 e1 = {0.f, 0.f, 0.f, 0.f};
        f32x4 e2 = {0.f, 0.f, 0.f, 0.f};
        f32x4 e3 = {0.f, 0.f, 0.f, 0.f};
        e0 = __builtin_amdgcn_mfma_f32_16x16x32_f16(a2[0][0], f0, e0, 0, 0, 0);
        e1 = __builtin_amdgcn_mfma_f32_16x16x32_f16(a2[1][0], f0, e1, 0, 0, 0);
        e2 = __builtin_amdgcn_mfma_f32_16x16x32_f16(a2[2][0], f0, e2, 0, 0, 0);
        e3 = __builtin_amdgcn_mfma_f32_16x16x32_f16(a2[3][0], f0, e3, 0, 0, 0);
        e0 = __builtin_amdgcn_mfma_f32_16x16x32_f16(a2[0][1], f1, e0, 0, 0, 0);
        e1 = __builtin_amdgcn_mfma_f32_16x16x32_f16(a2[1][1], f1, e1, 0, 0, 0);
        e2 = __builtin_amdgcn_mfma_f32_16x16x32_f16(a2[2][1], f1, e2, 0, 0, 0);
        e3 = __builtin_amdgcn_mfma_f32_16x16x32_f16(a2[3][1], f1, e3, 0, 0, 0);
        if (o == 0) {
            #pragma unroll
            for (int Mt = 0; Mt < 4; ++Mt) {
                f32x4 ee = (Mt == 0) ? e0 : (Mt == 1) ? e1 : (Mt == 2) ? e2 : e3;
                #pragma unroll
                for (int r = 0; r < 4; ++r) {
                    const int row = 16 * Mt + 4 * g + r;
                    *(float*)(slice + SIGO + row * 4) = fmaf(ee[r], 0.125f, bv);
                }
            }
        } else if (o < 33) {
            #pragma unroll
            for (int Mt = 0; Mt < 4; ++Mt) {
                f32x4 ee = (Mt == 0) ? e0 : (Mt == 1) ? e1 : (Mt == 2) ? e2 : e3;
                #pragma unroll
                for (int r = 0; r < 4; ++r) {
                    const float vv = fmaf(ee[r], 0.125f, bv);
                    const float rr = sigmoid_f(vv) * 1.002f - 0.001f;
                    const int row = 16 * Mt + 4 * g + r;
                    *(__half*)(slice + row * 80 + (o - 1) * 2) = __float2half(rr);
                }
            }
        }
    }

    // ---- coalesced REGULAR stores of rgb + sigma ----
    const int q0 = l & 3, r0 = l >> 2;
    #pragma unroll
    for (int q = 0; q < 4; ++q) {
        const int row = 16 * q + r0;
        i32x4 v = *(const i32x4*)(slice + row * 80 + q0 * 16);
        *(i32x4*)((char*)rgbW + (size_t)(waveBaseS + row) * 64 + q0 * 16) = v;
    }
    sigW[waveBaseS + l] = *(const float*)(slice + SIGO + l * 4);
}

// ============== split path: composite ==============
// r14 structure: regular loads + chunked depth-8 prefetch.
__global__ __launch_bounds__(512)
void k_comp(const __half* __restrict__ rgbW, const float* __restrict__ sigW,
            const float* __restrict__ depths, float* __restrict__ out)
{
    __shared__ float sgS[16 * SAMP];
    __shared__ float dpS[16 * SAMP];
    const int t = threadIdx.x;
    const int rayBase = blockIdx.x * 16;
    for (int i = t; i < 16 * SAMP; i += 512) {
        sgS[i] = sigW[(size_t)rayBase * SAMP + i];
        dpS[i] = depths[(size_t)rayBase * SAMP + i];
    }
    __syncthreads();

    const int rs = t >> 5;          // ray slot 0..15
    const int c = t & 31;           // channel
    const size_t mb = (size_t)(rayBase + rs) * SAMP;
    const __half* rgbp = rgbW + mb * 32 + c;

    float T = 1.f, a_out = 0.f;
    float sp = sgS[rs * SAMP], dp = dpS[rs * SAMP];
    float rp = __half2float(rgbp[0]);

    for (int chk = 0; chk < 12; ++chk) {
        const int sbeg = chk * 8 + 1;              // first mid-index in chunk
        __half h[8];
        #pragma unroll
        for (int j = 0; j < 8; ++j) {
            const int ss = min(sbeg + j, SAMP - 1);
            h[j] = rgbp[(size_t)ss * 32];          // 8 independent loads in flight
        }
        #pragma unroll
        for (int j = 0; j < 8; ++j) {
            const int ss = sbeg + j;
            if (ss >= SAMP) break;                 // uniform; last chunk only
            const float rc = __half2float(h[j]);
            const float sc = sgS[rs * SAMP + ss];
            const float dc = dpS[rs * SAMP + ss];
            const float dens = softplus_f(0.5f * (sp + sc) - 1.f);
            const float alpha = 1.f - __expf(-(dc - dp) * dens);
            a_out = fmaf(alpha * T, 0.5f * (rp + rc), a_out);
            T *= 1.f - alpha + 1e-10f;
            sp = sc; dp = dc; rp = rc;
        }
    }
    out[(size_t)(rayBase + rs) * CF + c] = fmaf(a_out, 2.f, -1.f);
}

// ============== fallback: direct from planes (no workspace) ==============
constexpr int THREADS = 384;
constexpr int SLICE = 9216;
constexpr int SIG_OFF = 5120;
constexpr int DEP_OFF = 5376;

__device__ __forceinline__ void mlp_slice(char* slice, const f16x8 a1[4],
                                          const Wreg& w, int g, int ln) {
    #pragma unroll
    for (int Nt = 0; Nt < 4; ++Nt) {
        f32x4 d0 = {0.f, 0.f, 0.f, 0.f};
        f32x4 d1 = {0.f, 0.f, 0.f, 0.f};
        f32x4 d2 = {0.f, 0.f, 0.f, 0.f};
        f32x4 d3 = {0.f, 0.f, 0.f, 0.f};
        d0 = __builtin_amdgcn_mfma_f32_16x16x32_f16(a1[0], w.b1f[Nt], d0, 0, 0, 0);
        d1 = __builtin_amdgcn_mfma_f32_16x16x32_f16(a1[1], w.b1f[Nt], d1, 0, 0, 0);
        d2 = __builtin_amdgcn_mfma_f32_16x16x32_f16(a1[2], w.b1f[Nt], d2, 0, 0, 0);
        d3 = __builtin_amdgcn_mfma_f32_16x16x32_f16(a1[3], w.b1f[Nt], d3, 0, 0, 0);
        const int hcol = 16 * Nt + ln;
        #pragma unroll
        for (int Mt = 0; Mt < 4; ++Mt) {
            f32x4 dd = (Mt == 0) ? d0 : (Mt == 1) ? d1 : (Mt == 2) ? d2 : d3;
            #pragma unroll
            for (int r = 0; r < 4; ++r) {
                const float hv = softplus_f(fmaf(dd[r], IS32_3, w.b1v[Nt]));
                const int row = 16 * Mt + 4 * g + r;
                *(__half*)(slice + row * 144 + hcol * 2) = __float2half(hv);
            }
        }
    }

    f16x8 a2[4][2];
    #pragma unroll
    for (int Mt = 0; Mt < 4; ++Mt)
        #pragma unroll
        for (int kh = 0; kh < 2; ++kh)
            a2[Mt][kh] = *(const f16x8*)(slice + (16 * Mt + ln) * 144 + (kh * 4 + g) * 16);

    #pragma unroll
    for (int Nt2 = 0; Nt2 < 3; ++Nt2) {
        f32x4 e0 = {0.f, 0.f, 0.f, 0.f};
        f32x4 e1 = {0.f, 0.f, 0.f, 0.f};
        f32x4 e2 = {0.f, 0.f, 0.f, 0.f};
        f32x4 e3 = {0.f, 0.f, 0.f, 0.f};
        #pragma unroll
        for (int kh = 0; kh < 2; ++kh) {
            e0 = __builtin_amdgcn_mfma_f32_16x16x32_f16(a2[0][kh], w.b2f[Nt2][kh], e0, 0, 0, 0);
            e1 = __builtin_amdgcn_mfma_f32_16x16x32_f16(a2[1][kh], w.b2f[Nt2][kh], e1, 0, 0, 0);
            e2 = __builtin_amdgcn_mfma_f32_16x16x32_f16(a2[2][kh], w.b2f[Nt2][kh], e2, 0, 0, 0);
            e3 = __builtin_amdgcn_mfma_f32_16x16x32_f16(a2[3][kh], w.b2f[Nt2][kh], e3, 0, 0, 0);
        }
        const int o = 16 * Nt2 + ln;
        if (o == 0) {
            #pragma unroll
            for (int Mt = 0; Mt < 4; ++Mt) {
                f32x4 ee = (Mt == 0) ? e0 : (Mt == 1) ? e1 : (Mt == 2) ? e2 : e3;
                #pragma unroll
                for (int r = 0; r < 4; ++r) {
                    const int row = 16 * Mt + 4 * g + r;
                    *(float*)(slice + SIG_OFF + row * 4) = fmaf(ee[r], 0.125f, w.b2v[0]);
                }
            }
        } else if (o < 33) {
            #pragma unroll
            for (int Mt = 0; Mt < 4; ++Mt) {
                f32x4 ee = (Mt == 0) ? e0 : (Mt == 1) ? e1 : (Mt == 2) ? e2 : e3;
                #pragma unroll
                for (int r = 0; r < 4; ++r) {
                    const float vv = fmaf(ee[r], 0.125f, w.b2v[Nt2]);
                    const float rr = sigmoid_f(vv) * 1.002f - 0.001f;
                    const int row = 16 * Mt + 4 * g + r;
                    *(__half*)(slice + row * 80 + (o - 1) * 2) = __float2half(rr);
                }
            }
        }
    }
}

__global__ __launch_bounds__(THREADS)
void k_fused(const float* __restrict__ planes,
             const float* __restrict__ coords, const float* __restrict__ depths,
             const float* __restrict__ w1, const float* __restrict__ b1,
             const float* __restrict__ w2, const float* __restrict__ b2,
             float* __restrict__ out)
{
    __shared__ __align__(16) char sm[6 * SLICE];
    const int t = threadIdx.x;
    const int wv = t >> 6;
    const int l = t & 63;
    const int g = l >> 4;
    const int ln = l & 15;
    char* const slice = sm + wv * SLICE;

    const int msamp = blockIdx.x * THREADS + t;
    const int nb = (msamp >= M_TOTAL / NB) ? 1 : 0;

    Wreg w;
    load_weights(w, w1, b1, w2, b2, g, ln);

    const float* cp = coords + (size_t)msamp * 3;
    const float c0 = cp[0], c1 = cp[1], c2v = cp[2];
    const float myDep = depths[msamp];

    float xf32[CF];
    #pragma unroll
    for (int c = 0; c < CF; ++c) xf32[c] = 0.f;

    #pragma unroll
    for (int p = 0; p < 3; ++p) {
        const float u = (p == 2) ? c2v : c0;
        const float v = (p == 0) ? c1 : ((p == 1) ? c2v : c0);
        const float xf = fmaf(u, 128.f, 127.5f);
        const float yf = fmaf(v, 128.f, 127.5f);
        const float x0f = floorf(xf), y0f = floorf(yf);
        const float wx = xf - x0f, wy = yf - y0f;
        const int x0 = (int)x0f, y0 = (int)y0f;
        const float vx0 = (x0 >= 0 && x0 < HW) ? 1.f : 0.f;
        const float vx1 = (x0 + 1 >= 0 && x0 + 1 < HW) ? 1.f : 0.f;
        const float vy0 = (y0 >= 0 && y0 < HW) ? 1.f : 0.f;
        const float vy1 = (y0 + 1 >= 0 && y0 + 1 < HW) ? 1.f : 0.f;
        const int xc0 = min(max(x0, 0), HW - 1), xc1 = min(max(x0 + 1, 0), HW - 1);
        const int yc0 = min(max(y0, 0), HW - 1), yc1 = min(max(y0 + 1, 0), HW - 1);
        const float w00 = (1.f - wx) * (1.f - wy) * vx0 * vy0;
        const float w10 = wx * (1.f - wy) * vx1 * vy0;
        const float w01 = (1.f - wx) * wy * vx0 * vy1;
        const float w11 = wx * wy * vx1 * vy1;

        const float* pb = planes + (((size_t)(nb * 3 + p) * CF) << 16);
        const int i00 = yc0 * HW + xc0, i10 = yc0 * HW + xc1;
        const int i01 = yc1 * HW + xc0, i11 = yc1 * HW + xc1;
        #pragma unroll
        for (int c = 0; c < CF; ++c) {
            const float* pc = pb + ((size_t)c << 16);
            float a0 = fmaf(w00, pc[i00], fmaf(w10, pc[i10], 0.f));
            float a1v = fmaf(w01, pc[i01], fmaf(w11, pc[i11], 0.f));
            xf32[c] += a0 + a1v;
        }
    }

    #pragma unroll
    for (int c = 0; c < 4; ++c) {
        union { __half2 h[4]; i32x4 v; } u4;
        #pragma unroll
        for (int j = 0; j < 4; ++j)
            u4.h[j] = __floats2half2_rn(xf32[8 * c + 2 * j], xf32[8 * c + 2 * j + 1]);
        *(i32x4*)(slice + l * 80 + c * 16) = u4.v;
    }

    f16x8 a1[4];
    #pragma unroll
    for (int Mt = 0; Mt < 4; ++Mt)
        a1[Mt] = *(const f16x8*)(slice + (16 * Mt + ln) * 80 + g * 16);

    mlp_slice(slice, a1, w, g, ln);
    *(float*)(slice + DEP_OFF + l * 4) = myDep;

    __syncthreads();

    if (t < 128) {
        const int crl = t >> 5;
        const int c = t & 31;
        const int bs = crl * SAMP;
        auto sigAt = [&](int sb) -> float {
            return *(const float*)(sm + (sb >> 6) * SLICE + SIG_OFF + (sb & 63) * 4);
        };
        auto depAt = [&](int sb) -> float {
            return *(const float*)(sm + (sb >> 6) * SLICE + DEP_OFF + (sb & 63) * 4);
        };
        auto rgbAt = [&](int sb) -> float {
            return __half2float(*(const __half*)(sm + (sb >> 6) * SLICE + (sb & 63) * 80 + c * 2));
        };
        float T = 1.f, a_out = 0.f;
        float sp = sigAt(bs), dp = depAt(bs), rp = rgbAt(bs);
        for (int ss = 1; ss < SAMP; ++ss) {
            const float sc = sigAt(bs + ss);
            const float dc = depAt(bs + ss);
            const float rc = rgbAt(bs + ss);
            const float dens = softplus_f(0.5f * (sp + sc) - 1.f);
            const float alpha = 1.f - __expf(-(dc - dp) * dens);
            a_out = fmaf(alpha * T, 0.5f * (rp + rc), a_out);
            T *= 1.f - alpha + 1e-10f;
            sp = sc; dp = dc; rp = rc;
        }
        out[(size_t)(blockIdx.x * 4 + crl) * CF + c] = fmaf(a_out, 2.f, -1.f);
    }
}

extern "C" void kernel_launch(void* const* d_in, const int* in_sizes, int n_in,
                              void* d_out, int out_size, void* d_ws, size_t ws_size,
                              hipStream_t stream) {
    (void)in_sizes; (void)n_in; (void)out_size;
    const float* planes = (const float*)d_in[0];
    const float* coords = (const float*)d_in[1];
    const float* depths = (const float*)d_in[2];
    const float* w1 = (const float*)d_in[3];
    const float* b1 = (const float*)d_in[4];
    const float* w2 = (const float*)d_in[5];
    const float* b2 = (const float*)d_in[6];
    float* out = (float*)d_out;

    const size_t ptBytes  = (size_t)NB * 3 * PTEX * CF * sizeof(__half);   // 25.56 MB
    const size_t rgbBytes = (size_t)M_TOTAL * CF * sizeof(__half);         // 50.33 MB
    const size_t sigBytes = (size_t)M_TOTAL * sizeof(float);               //  3.15 MB

    dim3 tgrid((PTEX + 255) / 256, NB * 3);   // (261, 6)

    if (ws_size >= ptBytes + rgbBytes + sigBytes) {
        __half2* pt = (__half2*)d_ws;
        __half* rgbW = (__half*)((char*)d_ws + ptBytes);
        float* sigW = (float*)((char*)d_ws + ptBytes + rgbBytes);
        k_transposeB<<<tgrid, 256, 0, stream>>>(planes, pt);
        k_gmlpB<<<M_TOTAL / TG, TG, 0, stream>>>(pt, coords, w1, b1, w2, b2, rgbW, sigW);
        k_comp<<<NB * RAYS / 16, 512, 0, stream>>>(rgbW, sigW, depths, out);
    } else {
        k_fused<<<M_TOTAL / THREADS, THREADS, 0, stream>>>(planes, coords, depths,
                                                           w1, b1, w2, b2, out);
    }
}